// Round 1
// baseline (3153.754 us; speedup 1.0000x reference)
//
#include <hip/hip_runtime.h>
#include <hip/hip_bf16.h>

#define MINF 1e-15f
#define EPSF 1e-6f

// ---------- workspace layout (floats) ----------
#define OFF_P    0u            // 16*2000*100      = 3,200,000
#define OFF_UX   3200000u      // 2*3*32000*100    = 19,200,000
#define OFF_WT4  22400000u     // 2*3*25*100*4     = 60,000
#define OFF_F    22460000u     // 16*20*100*200    = 6,400,000
#define OFF_CL   28860000u     // 201 (pad 256)
#define OFF_A    28860256u     // 32000
#define OFF_G    28892256u     // 32000
#define OFF_WGT  28924256u     // 32000
// total = 28,956,256 floats = 115.8 MB

#define K3_LDS_BYTES 149120    // (30000 + 13*3*112 + 13*112 + 13*112) * 4

__device__ __forceinline__ float wred(float v) {
#pragma unroll
  for (int m = 32; m > 0; m >>= 1) v += __shfl_xor(v, m, 64);
  return v;
}
__device__ __forceinline__ float wredmax(float v) {
#pragma unroll
  for (int m = 32; m > 0; m >>= 1) v = fmaxf(v, __shfl_xor(v, m, 64));
  return v;
}
__device__ __forceinline__ float artanh_c(float x) {
  x = fminf(x, 1.f - 1e-7f);
  return 0.5f * (log1pf(x) - log1pf(-x));
}
__device__ __forceinline__ float arcosh_(float x) {
  return logf(x) + log1pf(sqrtf(fmaxf(x * x - 1.f + EPSF, 0.f)) / x);
}
__device__ __forceinline__ float sigm(float x) { return 1.f / (1.f + expf(-x)); }

// ---------------- K0a: pack Whh into [dir][gate][k4][j][4] ----------------
__global__ void k0_pack(const float* __restrict__ whh_f, const float* __restrict__ whh_b,
                        float* __restrict__ wt4) {
  int idx = blockIdx.x * 256 + threadIdx.x;
  if (idx >= 60000) return;
  int kk = idx & 3; int t = idx >> 2;
  int j = t % 100; t /= 100;
  int k4 = t % 25; t /= 25;
  int g = t % 3; int dir = t / 3;
  const float* src = dir ? whh_b : whh_f;
  wt4[idx] = src[g * 10000 + j * 100 + k4 * 4 + kk];
}

// ---------------- K0b: lorentz_activation(centroid) -> cl[201] ----------------
__global__ void k0_cl(const float* __restrict__ centroid, float* __restrict__ cl) {
  __shared__ float sred[4];
  int t = threadIdx.x;
  float v = (t < 200) ? centroid[t] : 0.f;
  float ps = wred(v * v);
  if ((t & 63) == 0) sred[t >> 6] = ps;
  __syncthreads();
  float r = sqrtf(sred[0] + sred[1] + sred[2] + sred[3]);
  if (t < 200) cl[t] = v / r * sinhf(r);
  if (t == 0) cl[200] = coshf(r);
}

// ---------------- K1: klein(x_) @ W1^T + b1, poincare project -> p ----------------
// grid 800 (16 samples x 50 tiles of 40 rows), block 256
__global__ __launch_bounds__(256) void k1(const float* __restrict__ x_,
                                          const float* __restrict__ W1,
                                          const float* __restrict__ b1,
                                          float* __restrict__ p) {
  __shared__ float xt[40][36];
  __shared__ float wt[100][36];
  __shared__ float hbuf[40][104];
  __shared__ float ns[40];
  int bx = blockIdx.x; int n = bx / 50; int l0 = (bx % 50) * 40;
  int t = threadIdx.x;
  if (t < 40) ns[t] = 0.f;
  float nacc[5] = {0, 0, 0, 0, 0};
  int rg = t / 25, og = t % 25; bool act = t < 250;
  float acc[4][4];
#pragma unroll
  for (int i = 0; i < 4; i++)
#pragma unroll
    for (int j = 0; j < 4; j++) acc[i][j] = 0.f;
  const float* xbase = x_ + (size_t)(n * 2000 + l0) * 768;
  __syncthreads();
  for (int kc = 0; kc < 24; kc++) {
    int k0 = kc * 32;
#pragma unroll
    for (int q = 0; q < 5; q++) {
      int idx = t + 256 * q; int r = idx >> 5; int c = idx & 31;
      float v = xbase[(size_t)r * 768 + k0 + c];
      xt[r][c] = v; nacc[q] += v * v;
    }
#pragma unroll
    for (int q = 0; q < 13; q++) {
      int idx = t + 256 * q;
      if (idx < 3200) { int r = idx >> 5; int c = idx & 31; wt[r][c] = W1[(size_t)r * 768 + k0 + c]; }
    }
    __syncthreads();
    if (act) {
#pragma unroll
      for (int k4 = 0; k4 < 8; k4++) {
        float4 xv[4], wv[4];
#pragma unroll
        for (int i = 0; i < 4; i++) xv[i] = *(const float4*)&xt[rg * 4 + i][k4 * 4];
#pragma unroll
        for (int j = 0; j < 4; j++) wv[j] = *(const float4*)&wt[og + 25 * j][k4 * 4];
#pragma unroll
        for (int i = 0; i < 4; i++)
#pragma unroll
          for (int j = 0; j < 4; j++)
            acc[i][j] += xv[i].x * wv[j].x + xv[i].y * wv[j].y + xv[i].z * wv[j].z + xv[i].w * wv[j].w;
      }
    }
    __syncthreads();
  }
#pragma unroll
  for (int q = 0; q < 5; q++) atomicAdd(&ns[(t >> 5) + 8 * q], nacc[q]);
  __syncthreads();
  if (act) {
#pragma unroll
    for (int i = 0; i < 4; i++) {
      int r = rg * 4 + i;
      float rr = sqrtf(ns[r]); float s = tanhf(rr) / rr;
#pragma unroll
      for (int j = 0; j < 4; j++) {
        int jo = og + 25 * j;
        hbuf[r][jo] = s * acc[i][j] + b1[jo];
      }
    }
  }
  __syncthreads();
  int w = t >> 6, lane = t & 63;
  for (int rr = w * 10; rr < w * 10 + 10; rr++) {
    float h0 = hbuf[rr][lane];
    float h1 = (lane < 36) ? hbuf[rr][lane + 64] : 0.f;
    float s2 = wred(h0 * h0 + h1 * h1);
    float inv = 1.f / sqrtf(1.f + s2);
    float* prow = p + (size_t)(n * 2000 + l0 + rr) * 100;
    prow[lane] = h0 * inv;
    if (lane < 36) prow[lane + 64] = h1 * inv;
  }
}

// ---------------- K2: ux[dir][g][row] = m_matvec(Wih_dir[g], p[row]) ----------------
// grid 1334*6, block 256
__global__ __launch_bounds__(256) void k2(const float* __restrict__ p,
                                          const float* __restrict__ wih_f,
                                          const float* __restrict__ wih_b,
                                          float* __restrict__ ux) {
  __shared__ float pt[24][104];
  __shared__ float wt[100][108];
  __shared__ float alx[24];
  int bx = blockIdx.x; int tile = bx / 6; int combo = bx % 6;
  int dir = combo / 3, g = combo % 3;
  int row0 = tile * 24; int nrows = min(24, 32000 - row0);
  int t = threadIdx.x;
  const float* W = (dir ? wih_b : wih_f) + g * 10000;
#pragma unroll
  for (int q = 0; q < 10; q++) {
    int idx = t + 256 * q;
    if (idx < 2400) {
      int r = idx / 100, c = idx % 100;
      pt[r][c] = (r < nrows) ? p[(size_t)(row0 + r) * 100 + c] : 0.f;
    }
  }
#pragma unroll
  for (int q = 0; q < 40; q++) {
    int idx = t + 256 * q;
    if (idx < 10000) { int r = idx / 100, c = idx % 100; wt[r][c] = W[idx]; }
  }
  __syncthreads();
  int w = t >> 6, lane = t & 63;
  for (int r = w * 6; r < w * 6 + 6; r++) {
    float v0 = pt[r][lane], v1 = (lane < 36) ? pt[r][lane + 64] : 0.f;
    float s2 = wred(v0 * v0 + v1 * v1);
    if (lane == 0) {
      float xn = sqrtf(fmaxf(s2, MINF));
      alx[r] = artanh_c(xn) / xn;
    }
  }
  int rg = t / 25, og = t % 25; bool act = t < 200;
  float acc[3][4];
#pragma unroll
  for (int i = 0; i < 3; i++)
#pragma unroll
    for (int j = 0; j < 4; j++) acc[i][j] = 0.f;
  __syncthreads();
  if (act) {
#pragma unroll
    for (int k4 = 0; k4 < 25; k4++) {
      float4 pv[3], wv[4];
#pragma unroll
      for (int i = 0; i < 3; i++) pv[i] = *(const float4*)&pt[rg * 3 + i][k4 * 4];
#pragma unroll
      for (int j = 0; j < 4; j++) wv[j] = *(const float4*)&wt[og + 25 * j][k4 * 4];
#pragma unroll
      for (int i = 0; i < 3; i++)
#pragma unroll
        for (int j = 0; j < 4; j++)
          acc[i][j] += pv[i].x * wv[j].x + pv[i].y * wv[j].y + pv[i].z * wv[j].z + pv[i].w * wv[j].w;
    }
  }
  __syncthreads();
  if (act) {
#pragma unroll
    for (int i = 0; i < 3; i++)
#pragma unroll
      for (int j = 0; j < 4; j++) pt[rg * 3 + i][og + 25 * j] = acc[i][j];
  }
  __syncthreads();
  for (int r = w * 6; r < w * 6 + 6; r++) {
    if (r >= nrows) continue;
    float m0 = pt[r][lane], m1 = (lane < 36) ? pt[r][lane + 64] : 0.f;
    float s2 = wred(m0 * m0 + m1 * m1);
    float mxn = sqrtf(fmaxf(s2, MINF));
    float sc = tanhf(mxn * alx[r]) / mxn;
    float* dst = ux + ((size_t)(dir * 3 + g) * 32000 + row0 + r) * 100;
    dst[lane] = sc * m0;
    if (lane < 36) dst[lane + 64] = sc * m1;
  }
}

// ---------------- K3: sequential Mobius GRU ----------------
__device__ __forceinline__ void mv100(const float* __restrict__ Wg, const float* __restrict__ hrow,
                                      float* __restrict__ out, int lane) {
  const float4* W4 = (const float4*)Wg;
  const float4* h4 = (const float4*)hrow;
  float4 a0 = {0, 0, 0, 0}, a1 = {0, 0, 0, 0};
#pragma unroll
  for (int k4 = 0; k4 < 25; k4++) {
    float4 hv = h4[k4];
    float4 w0 = W4[k4 * 100 + lane];
    a0.x += w0.x * hv.x; a0.y += w0.y * hv.y; a0.z += w0.z * hv.z; a0.w += w0.w * hv.w;
    if (lane < 36) {
      float4 w1 = W4[k4 * 100 + lane + 64];
      a1.x += w1.x * hv.x; a1.y += w1.y * hv.y; a1.z += w1.z * hv.z; a1.w += w1.w * hv.w;
    }
  }
  out[lane] = a0.x + a0.y + a0.z + a0.w;
  if (lane < 36) out[64 + lane] = a1.x + a1.y + a1.z + a1.w;
}

// one_transform without bias-free parts: c = m_add(m_add(gamma*mv, ux), b)
__device__ __forceinline__ void onetrans(const float* __restrict__ mv, float ux0, float ux1,
                                         float alphax, float b_0, float b_1, float nb2, int lane,
                                         float& c0, float& c1) {
  float m0 = mv[lane];
  float m1 = (lane < 36) ? mv[64 + lane] : 0.f;
  float A = wred(m0 * m0 + m1 * m1);
  float B = wred(m0 * ux0 + m1 * ux1);
  float C = wred(ux0 * ux0 + ux1 * ux1);
  float mxn = sqrtf(fmaxf(A, MINF));
  float gam = tanhf(mxn * alphax) / mxn;
  float x2 = gam * gam * A, y2 = C, xy = gam * B;
  float rd = 1.f / fmaxf(1.f + 2.f * xy + x2 * y2, MINF);
  float cA = (1.f + 2.f * xy + y2) * gam * rd, cB = (1.f - x2) * rd;
  float a0 = cA * m0 + cB * ux0, a1 = cA * m1 + cB * ux1;
  float D = wred(a0 * a0 + a1 * a1);
  float E = wred(a0 * b_0 + a1 * b_1);
  float r2 = 1.f / fmaxf(1.f + 2.f * E + D * nb2, MINF);
  float t1 = (1.f + 2.f * E + nb2) * r2, t2 = (1.f - D) * r2;
  c0 = t1 * a0 + t2 * b_0;
  c1 = t1 * a1 + t2 * b_1;
}

// grid 256 (32 groups x 8 row-chunks), block 1024, dyn LDS 149120 B
__global__ __launch_bounds__(1024) void k3(const float* __restrict__ ux,
                                           const float* __restrict__ wt4,
                                           const float* __restrict__ bias_f,
                                           const float* __restrict__ bias_b,
                                           float* __restrict__ f) {
  extern __shared__ float lds[];
  float* Wlds = lds;                 // 30000
  float* mvl = lds + 30000;          // 13*3*112
  float* hl = mvl + 13 * 3 * 112;    // 13*112
  float* rhl = hl + 13 * 112;        // 13*112
  int t = threadIdx.x; int w = t >> 6; int lane = t & 63;
  int bx = blockIdx.x;
  int grp = bx >> 3; int blki = bx & 7;
  int n = grp >> 1; int dir = grp & 1;
  int b0 = blki * 13; int nrows = min(13, 100 - b0);
  const float* bias = dir ? bias_b : bias_f;
  const float* wsrc = wt4 + dir * 30000;
#pragma unroll
  for (int q = 0; q < 30; q++) { int idx = t + 1024 * q; if (idx < 30000) Wlds[idx] = wsrc[idx]; }
#pragma unroll
  for (int q = 0; q < 2; q++) { int idx = t + 1024 * q; if (idx < 13 * 112) hl[idx] = 0.f; }
  __syncthreads();

  int row = w; bool erow = (w < nrows);
  int b = b0 + row;
  float nh2 = 0.f, h0 = 0.f, h1 = 0.f;
  float bz0 = 0, bz1 = 0, br0 = 0, br1 = 0, bh0 = 0, bh1 = 0, nbz2 = 0, nbr2 = 0, nbh2 = 0;
  if (erow) {
    br0 = bias[lane];        if (lane < 36) br1 = bias[64 + lane];
    bh0 = bias[100 + lane];  if (lane < 36) bh1 = bias[164 + lane];
    bz0 = bias[200 + lane];  if (lane < 36) bz1 = bias[264 + lane];
    nbr2 = wred(br0 * br0 + br1 * br1);
    nbh2 = wred(bh0 * bh0 + bh1 * bh1);
    nbz2 = wred(bz0 * bz0 + bz1 * bz1);
  }
  for (int s = 0; s < 20; s++) {
    // M1: matvecs for z (g=2) and r (g=0) gates, distributed to all 16 waves
    for (int ti = w; ti < nrows * 2; ti += 16) {
      int mrow = ti >> 1; int g = (ti & 1) ? 0 : 2;
      mv100(Wlds + g * 10000, hl + mrow * 112, mvl + (mrow * 3 + g) * 112, lane);
    }
    __syncthreads();
    float z0 = 0, z1 = 0, uxh0 = 0, uxh1 = 0, nrh2 = 0;
    if (erow) {
      int l = dir ? (1999 - (s * 100 + b)) : (s * 100 + b);
      size_t rowg = (size_t)n * 2000 + l;
      const float* uxz = ux + ((size_t)(dir * 3 + 2) * 32000 + rowg) * 100;
      const float* uxr = ux + ((size_t)(dir * 3 + 0) * 32000 + rowg) * 100;
      const float* uxh = ux + ((size_t)(dir * 3 + 1) * 32000 + rowg) * 100;
      float uz0 = uxz[lane], uz1 = (lane < 36) ? uxz[lane + 64] : 0.f;
      float ur0 = uxr[lane], ur1 = (lane < 36) ? uxr[lane + 64] : 0.f;
      uxh0 = uxh[lane]; uxh1 = (lane < 36) ? uxh[lane + 64] : 0.f;
      float xnh = sqrtf(fmaxf(nh2, MINF));
      float alphah = artanh_c(xnh) / xnh;
      float cz0, cz1, cr0, cr1;
      onetrans(mvl + (row * 3 + 2) * 112, uz0, uz1, alphah, bz0, bz1, nbz2, lane, cz0, cz1);
      onetrans(mvl + (row * 3 + 0) * 112, ur0, ur1, alphah, br0, br1, nbr2, lane, cr0, cr1);
      float Fz = wred(cz0 * cz0 + cz1 * cz1);
      float cnz = sqrtf(fmaxf(Fz, MINF)); float lgz = artanh_c(cnz) / cnz;
      z0 = sigm(lgz * cz0); z1 = sigm(lgz * cz1);
      float Fr = wred(cr0 * cr0 + cr1 * cr1);
      float cnr = sqrtf(fmaxf(Fr, MINF)); float lgr = artanh_c(cnr) / cnr;
      float r0 = sigm(lgr * cr0), r1 = sigm(lgr * cr1);
      // rh = m_pw(r, h)
      float mx0 = r0 * h0, mx1 = r1 * h1;
      float G = wred(mx0 * mx0 + mx1 * mx1);
      float mxnr = sqrtf(fmaxf(G, MINF));
      float srh = tanhf(mxnr * alphah) / mxnr;
      rhl[row * 112 + lane] = srh * mx0;
      if (lane < 36) rhl[row * 112 + lane + 64] = srh * mx1;
      nrh2 = srh * srh * G;
      // M2 (own row): htil matvec — same wave wrote rhl, no barrier needed
      mv100(Wlds + 1 * 10000, rhl + row * 112, mvl + (row * 3 + 1) * 112, lane);
      // E2
      float xnrh = sqrtf(fmaxf(nrh2, MINF));
      float alpharh = artanh_c(xnrh) / xnrh;
      float ct0, ct1;
      onetrans(mvl + (row * 3 + 1) * 112, uxh0, uxh1, alpharh, bh0, bh1, nbh2, lane, ct0, ct1);
      // d = m_add(-h, htil)
      float T = wred(ct0 * ct0 + ct1 * ct1);
      float U = wred(h0 * ct0 + h1 * ct1);
      float rd = 1.f / fmaxf(1.f - 2.f * U + nh2 * T, MINF);
      float cA = (1.f - 2.f * U + T) * rd, cB = (1.f - nh2) * rd;
      float d0 = -cA * h0 + cB * ct0, d1 = -cA * h1 + cB * ct1;
      // pw = m_pw(z, d)
      float zd0 = z0 * d0, zd1 = z1 * d1;
      float nd2 = wred(d0 * d0 + d1 * d1);
      float P = wred(zd0 * zd0 + zd1 * zd1);
      float Q = wred(h0 * zd0 + h1 * zd1);
      float xnd = sqrtf(fmaxf(nd2, MINF));
      float mxnp = sqrtf(fmaxf(P, MINF));
      float sp = tanhf(mxnp * artanh_c(xnd) / xnd) / mxnp;
      float pw0 = sp * zd0, pw1 = sp * zd1;
      float y2 = sp * sp * P, xy = sp * Q;
      float r3 = 1.f / fmaxf(1.f + 2.f * xy + nh2 * y2, MINF);
      float hn0 = (1.f + 2.f * xy + y2) * r3 * h0 + (1.f - nh2) * r3 * pw0;
      float hn1 = (1.f + 2.f * xy + y2) * r3 * h1 + (1.f - nh2) * r3 * pw1;
      nh2 = wred(hn0 * hn0 + hn1 * hn1);
      h0 = hn0; h1 = hn1;
      hl[row * 112 + lane] = hn0;
      if (lane < 36) hl[row * 112 + lane + 64] = hn1;
      float* fd = f + (((size_t)n * 20 + s) * 100 + b) * 200 + dir * 100;
      fd[lane] = hn0;
      if (lane < 36) fd[lane + 64] = hn1;
    }
    __syncthreads();
  }
}

// ---------------- K4a: MobiusLinear(Wp) + lorentz logits a, gamma ----------------
// grid 1334, block 256
__global__ __launch_bounds__(256) void k4a(const float* __restrict__ f, const float* __restrict__ Wp,
                                           const float* __restrict__ bp, const float* __restrict__ cl,
                                           const float* __restrict__ beta_p,
                                           float* __restrict__ a_out, float* __restrict__ g_out) {
  __shared__ float ft[24][208];
  __shared__ float wt[200][44];
  __shared__ float alx[24];
  __shared__ float nf2s[24];
  int bx = blockIdx.x; int row0 = bx * 24; int nrows = min(24, 32000 - row0);
  int t = threadIdx.x; int w = t >> 6; int lane = t & 63;
#pragma unroll
  for (int q = 0; q < 19; q++) {
    int idx = t + 256 * q;
    if (idx < 4800) {
      int r = idx / 200, c = idx % 200;
      ft[r][c] = (r < nrows) ? f[(size_t)(row0 + r) * 200 + c] : 0.f;
    }
  }
  __syncthreads();
  for (int r = w * 6; r < w * 6 + 6; r++) {
    float v0 = ft[r][lane], v1 = ft[r][lane + 64], v2 = ft[r][lane + 128];
    float v3 = (lane < 8) ? ft[r][lane + 192] : 0.f;
    float s2 = wred(v0 * v0 + v1 * v1 + v2 * v2 + v3 * v3);
    if (lane == 0) {
      nf2s[r] = s2;
      float xn = sqrtf(fmaxf(s2, MINF));
      alx[r] = artanh_c(xn) / xn;
    }
  }
  int rg = t / 25, og = t % 25; bool act = t < 200;
  float acc[3][8];
#pragma unroll
  for (int i = 0; i < 3; i++)
#pragma unroll
    for (int j = 0; j < 8; j++) acc[i][j] = 0.f;
  for (int kc = 0; kc < 5; kc++) {
    int k0 = kc * 40;
    __syncthreads();
#pragma unroll
    for (int q = 0; q < 32; q++) {
      int idx = t + 256 * q;
      if (idx < 8000) { int r = idx / 40, c = idx % 40; wt[r][c] = Wp[(size_t)r * 200 + k0 + c]; }
    }
    __syncthreads();
    if (act) {
#pragma unroll
      for (int k4 = 0; k4 < 10; k4++) {
        float4 pv[3];
#pragma unroll
        for (int i = 0; i < 3; i++) pv[i] = *(const float4*)&ft[rg * 3 + i][k0 + k4 * 4];
#pragma unroll
        for (int j = 0; j < 8; j++) {
          float4 wv = *(const float4*)&wt[og + 25 * j][k4 * 4];
#pragma unroll
          for (int i = 0; i < 3; i++)
            acc[i][j] += pv[i].x * wv.x + pv[i].y * wv.y + pv[i].z * wv.z + pv[i].w * wv.w;
        }
      }
    }
  }
  __syncthreads();
  if (act) {
#pragma unroll
    for (int i = 0; i < 3; i++)
#pragma unroll
      for (int j = 0; j < 8; j++) ft[rg * 3 + i][og + 25 * j] = acc[i][j];
  }
  __syncthreads();
  float beta = beta_p[0];
  float c200 = cl[200];
  float b_0 = bp[lane], b_1 = bp[lane + 64], b_2 = bp[lane + 128];
  float b_3 = (lane < 8) ? bp[lane + 192] : 0.f;
  float c_0 = cl[lane], c_1 = cl[lane + 64], c_2 = cl[lane + 128];
  float c_3 = (lane < 8) ? cl[lane + 192] : 0.f;
  float nbp2 = wred(b_0 * b_0 + b_1 * b_1 + b_2 * b_2 + b_3 * b_3);
  for (int r = w * 6; r < w * 6 + 6; r++) {
    if (r >= nrows) continue;
    float m0 = ft[r][lane], m1 = ft[r][lane + 64], m2 = ft[r][lane + 128];
    float m3 = (lane < 8) ? ft[r][lane + 192] : 0.f;
    float A = wred(m0 * m0 + m1 * m1 + m2 * m2 + m3 * m3);
    float B = wred(m0 * b_0 + m1 * b_1 + m2 * b_2 + m3 * b_3);
    float mxn = sqrtf(fmaxf(A, MINF));
    float gam = tanhf(mxn * alx[r]) / mxn;
    float x2 = gam * gam * A, y2 = nbp2, xy = gam * B;
    float rd = 1.f / fmaxf(1.f + 2.f * xy + x2 * y2, MINF);
    float cA = (1.f + 2.f * xy + y2) * gam * rd, cB = (1.f - x2) * rd;
    float a0 = cA * m0 + cB * b_0, a1 = cA * m1 + cB * b_1;
    float a2 = cA * m2 + cB * b_2, a3 = cA * m3 + cB * b_3;
    float r2 = wred(a0 * a0 + a1 * a1 + a2 * a2 + a3 * a3);
    float dc = wred(a0 * c_0 + a1 * c_1 + a2 * c_2 + a3 * c_3);
    float pm = (-2.f * dc + (1.f + r2) * c200) / (1.f - r2 + EPSF);
    pm = fminf(fmaxf(pm, 1.f + EPSF), 1e16f);
    float av = -beta * arcosh_(pm) - 1.f;
    float nf2 = nf2s[r];
    float invg = 1.f - 4.f * nf2 / ((1.f + nf2) * (1.f + nf2));
    invg = fminf(fmaxf(invg, EPSF), 1.f - EPSF);
    float gv = fminf(fmaxf(1.f / sqrtf(invg), 1.f + EPSF), 1e16f);
    if (lane == 0) { a_out[row0 + r] = av; g_out[row0 + r] = gv; }
  }
}

// ---------------- K4b: per-sample softmax weights ----------------
// grid 16, block 256
__global__ __launch_bounds__(256) void k4b(const float* __restrict__ a_in,
                                           const float* __restrict__ g_in,
                                           float* __restrict__ wgt) {
  __shared__ float rl[2000];
  __shared__ float sred[4];
  __shared__ float rsinv[100];
  int n = blockIdx.x; int t = threadIdx.x;
  int w = t >> 6, lane = t & 63;
  const float* ap = a_in + n * 2000;
  const float* gp = g_in + n * 2000;
  float av[8]; float am = -1e30f;
#pragma unroll
  for (int q = 0; q < 8; q++) {
    int i = t + 256 * q;
    av[q] = (i < 2000) ? ap[i] : -1e30f;
    am = fmaxf(am, av[q]);
  }
  am = wredmax(am);
  if (lane == 0) sred[w] = am;
  __syncthreads();
  float amax = fmaxf(fmaxf(sred[0], sred[1]), fmaxf(sred[2], sred[3]));
#pragma unroll
  for (int q = 0; q < 8; q++) {
    int i = t + 256 * q;
    if (i < 2000) rl[i] = expf(av[q] - amax) * gp[i];
  }
  __syncthreads();
  if (t < 100) {
    float ssum = 0.f;
#pragma unroll
    for (int s = 0; s < 20; s++) ssum += rl[s * 100 + t];
    rsinv[t] = 1.f / ssum;
  }
  __syncthreads();
#pragma unroll
  for (int q = 0; q < 8; q++) {
    int i = t + 256 * q;
    if (i < 2000) wgt[n * 2000 + i] = rl[i] * rsinv[i % 100];
  }
}

// ---------------- K4c: klein aggregation + final GEMM W2 ----------------
// grid 320 (n,s), block 256
__global__ __launch_bounds__(256) void k4c(const float* __restrict__ f, const float* __restrict__ wgt,
                                           const float* __restrict__ W2, const float* __restrict__ b2,
                                           float* __restrict__ out) {
  __shared__ float cw[100];
  __shared__ float ol[200];
  __shared__ float sred[4];
  int bx = blockIdx.x; int n = bx / 20, s = bx % 20;
  int t = threadIdx.x; int w = t >> 6; int lane = t & 63;
  const float* fb = f + ((size_t)n * 20 + s) * 100 * 200;
  for (int bi = w * 25; bi < w * 25 + 25; bi++) {
    const float* fr = fb + bi * 200;
    float v0 = fr[lane], v1 = fr[lane + 64], v2 = fr[lane + 128];
    float v3 = (lane < 8) ? fr[lane + 192] : 0.f;
    float s2 = wred(v0 * v0 + v1 * v1 + v2 * v2 + v3 * v3);
    if (lane == 0) cw[bi] = wgt[n * 2000 + s * 100 + bi] * 2.f / (1.f + s2);
  }
  __syncthreads();
  float o = 0.f;
  if (t < 200) {
    for (int bi = 0; bi < 100; bi++) o += cw[bi] * fb[bi * 200 + t];
  }
  float ps = (t < 200) ? o * o : 0.f;
  ps = wred(ps);
  if (lane == 0) sred[w] = ps;
  __syncthreads();
  float no2 = sred[0] + sred[1] + sred[2] + sred[3];
  float denom = 1.f + sqrtf(1.f + no2);
  if (t < 200) ol[t] = o / denom;
  __syncthreads();
  const float4* ol4 = (const float4*)ol;
#pragma unroll
  for (int jj = 0; jj < 3; jj++) {
    int j = t + 256 * jj;
    const float4* wrow = (const float4*)(W2 + (size_t)j * 200);
    float a0 = 0, a1 = 0, a2 = 0, a3 = 0;
    for (int k4 = 0; k4 < 50; k4++) {
      float4 wv = wrow[k4]; float4 ov = ol4[k4];
      a0 += wv.x * ov.x; a1 += wv.y * ov.y; a2 += wv.z * ov.z; a3 += wv.w * ov.w;
    }
    out[((size_t)n * 20 + s) * 768 + j] = a0 + a1 + a2 + a3 + b2[j];
  }
}

extern "C" void kernel_launch(void* const* d_in, const int* in_sizes, int n_in,
                              void* d_out, int out_size, void* d_ws, size_t ws_size,
                              hipStream_t stream) {
  const float* x_     = (const float*)d_in[0];
  const float* W1     = (const float*)d_in[1];
  const float* b1     = (const float*)d_in[2];
  const float* W2     = (const float*)d_in[3];
  const float* b2     = (const float*)d_in[4];
  const float* Wih_f  = (const float*)d_in[5];
  const float* Whh_f  = (const float*)d_in[6];
  const float* bias_f = (const float*)d_in[7];
  const float* Wih_b  = (const float*)d_in[8];
  const float* Whh_b  = (const float*)d_in[9];
  const float* bias_b = (const float*)d_in[10];
  const float* centroid = (const float*)d_in[11];
  const float* Wp     = (const float*)d_in[12];
  const float* bp     = (const float*)d_in[13];
  const float* beta   = (const float*)d_in[14];
  float* out = (float*)d_out;
  float* ws = (float*)d_ws;
  float* p   = ws + OFF_P;
  float* ux  = ws + OFF_UX;
  float* wt4 = ws + OFF_WT4;
  float* f   = ws + OFF_F;
  float* cl  = ws + OFF_CL;
  float* aa  = ws + OFF_A;
  float* gg  = ws + OFF_G;
  float* wg  = ws + OFF_WGT;

  (void)hipFuncSetAttribute(reinterpret_cast<const void*>(k3),
                            hipFuncAttributeMaxDynamicSharedMemorySize, K3_LDS_BYTES);

  k0_pack<<<235, 256, 0, stream>>>(Whh_f, Whh_b, wt4);
  k0_cl<<<1, 256, 0, stream>>>(centroid, cl);
  k1<<<800, 256, 0, stream>>>(x_, W1, b1, p);
  k2<<<8004, 256, 0, stream>>>(p, Wih_f, Wih_b, ux);
  k3<<<256, 1024, K3_LDS_BYTES, stream>>>(ux, wt4, bias_f, bias_b, f);
  k4a<<<1334, 256, 0, stream>>>(f, Wp, bp, cl, beta, aa, gg);
  k4b<<<16, 256, 0, stream>>>(aa, gg, wg);
  k4c<<<320, 256, 0, stream>>>(f, wg, W2, b2, out);
}

// Round 2
// 1674.434 us; speedup vs baseline: 1.8835x; 1.8835x over previous
//
#include <hip/hip_runtime.h>
#include <hip/hip_bf16.h>

#define MINF 1e-15f
#define EPSF 1e-6f

// ---------- workspace layout (floats) ----------
#define OFF_P    0u            // 16*2000*100      = 3,200,000
#define OFF_UX   3200000u      // 2*3*32000*100    = 19,200,000
#define OFF_WT4  22400000u     // 2*3*25*100*4     = 60,000
#define OFF_F    22460000u     // 16*20*100*200    = 6,400,000
#define OFF_CL   28860000u     // 201 (pad 256)
#define OFF_A    28860256u     // 32000
#define OFF_G    28892256u     // 32000
#define OFF_WGT  28924256u     // 32000
// total = 28,956,256 floats = 115.8 MB

#define K3_LDS_BYTES 149120    // (30000 + 13*3*112 + 13*112 + 13*112) * 4

__device__ __forceinline__ float wred(float v) {
#pragma unroll
  for (int m = 32; m > 0; m >>= 1) v += __shfl_xor(v, m, 64);
  return v;
}
__device__ __forceinline__ float wredmax(float v) {
#pragma unroll
  for (int m = 32; m > 0; m >>= 1) v = fmaxf(v, __shfl_xor(v, m, 64));
  return v;
}
__device__ __forceinline__ float artanh_c(float x) {
  x = fminf(x, 1.f - 1e-7f);
  return 0.5f * (log1pf(x) - log1pf(-x));
}
__device__ __forceinline__ float arcosh_(float x) {
  return logf(x) + log1pf(sqrtf(fmaxf(x * x - 1.f + EPSF, 0.f)) / x);
}
__device__ __forceinline__ float sigm(float x) { return 1.f / (1.f + expf(-x)); }

// ---------------- K0a: pack Whh into [dir][gate][k4][j][4] ----------------
__global__ void k0_pack(const float* __restrict__ whh_f, const float* __restrict__ whh_b,
                        float* __restrict__ wt4) {
  int idx = blockIdx.x * 256 + threadIdx.x;
  if (idx >= 60000) return;
  int kk = idx & 3; int t = idx >> 2;
  int j = t % 100; t /= 100;
  int k4 = t % 25; t /= 25;
  int g = t % 3; int dir = t / 3;
  const float* src = dir ? whh_b : whh_f;
  wt4[idx] = src[g * 10000 + j * 100 + k4 * 4 + kk];
}

// ---------------- K0b: lorentz_activation(centroid) -> cl[201] ----------------
__global__ void k0_cl(const float* __restrict__ centroid, float* __restrict__ cl) {
  __shared__ float sred[4];
  int t = threadIdx.x;
  float v = (t < 200) ? centroid[t] : 0.f;
  float ps = wred(v * v);
  if ((t & 63) == 0) sred[t >> 6] = ps;
  __syncthreads();
  float r = sqrtf(sred[0] + sred[1] + sred[2] + sred[3]);
  if (t < 200) cl[t] = v / r * sinhf(r);
  if (t == 0) cl[200] = coshf(r);
}

// ---------------- K1: klein(x_) @ W1^T + b1, poincare project -> p ----------------
// grid 800 (16 samples x 50 tiles of 40 rows), block 256
__global__ __launch_bounds__(256) void k1(const float* __restrict__ x_,
                                          const float* __restrict__ W1,
                                          const float* __restrict__ b1,
                                          float* __restrict__ p) {
  __shared__ float xt[40][36];
  __shared__ float wt[100][36];
  __shared__ float hbuf[40][104];
  __shared__ float ns[40];
  int bx = blockIdx.x; int n = bx / 50; int l0 = (bx % 50) * 40;
  int t = threadIdx.x;
  if (t < 40) ns[t] = 0.f;
  float nacc[5] = {0, 0, 0, 0, 0};
  int rg = t / 25, og = t % 25; bool act = t < 250;
  float acc[4][4];
#pragma unroll
  for (int i = 0; i < 4; i++)
#pragma unroll
    for (int j = 0; j < 4; j++) acc[i][j] = 0.f;
  const float* xbase = x_ + (size_t)(n * 2000 + l0) * 768;
  __syncthreads();
  for (int kc = 0; kc < 24; kc++) {
    int k0 = kc * 32;
#pragma unroll
    for (int q = 0; q < 5; q++) {
      int idx = t + 256 * q; int r = idx >> 5; int c = idx & 31;
      float v = xbase[(size_t)r * 768 + k0 + c];
      xt[r][c] = v; nacc[q] += v * v;
    }
#pragma unroll
    for (int q = 0; q < 13; q++) {
      int idx = t + 256 * q;
      if (idx < 3200) { int r = idx >> 5; int c = idx & 31; wt[r][c] = W1[(size_t)r * 768 + k0 + c]; }
    }
    __syncthreads();
    if (act) {
#pragma unroll
      for (int k4 = 0; k4 < 8; k4++) {
        float4 xv[4], wv[4];
#pragma unroll
        for (int i = 0; i < 4; i++) xv[i] = *(const float4*)&xt[rg * 4 + i][k4 * 4];
#pragma unroll
        for (int j = 0; j < 4; j++) wv[j] = *(const float4*)&wt[og + 25 * j][k4 * 4];
#pragma unroll
        for (int i = 0; i < 4; i++)
#pragma unroll
          for (int j = 0; j < 4; j++)
            acc[i][j] += xv[i].x * wv[j].x + xv[i].y * wv[j].y + xv[i].z * wv[j].z + xv[i].w * wv[j].w;
      }
    }
    __syncthreads();
  }
#pragma unroll
  for (int q = 0; q < 5; q++) atomicAdd(&ns[(t >> 5) + 8 * q], nacc[q]);
  __syncthreads();
  if (act) {
#pragma unroll
    for (int i = 0; i < 4; i++) {
      int r = rg * 4 + i;
      float rr = sqrtf(ns[r]); float s = tanhf(rr) / rr;
#pragma unroll
      for (int j = 0; j < 4; j++) {
        int jo = og + 25 * j;
        hbuf[r][jo] = s * acc[i][j] + b1[jo];
      }
    }
  }
  __syncthreads();
  int w = t >> 6, lane = t & 63;
  for (int rr = w * 10; rr < w * 10 + 10; rr++) {
    float h0 = hbuf[rr][lane];
    float h1 = (lane < 36) ? hbuf[rr][lane + 64] : 0.f;
    float s2 = wred(h0 * h0 + h1 * h1);
    float inv = 1.f / sqrtf(1.f + s2);
    float* prow = p + (size_t)(n * 2000 + l0 + rr) * 100;
    prow[lane] = h0 * inv;
    if (lane < 36) prow[lane + 64] = h1 * inv;
  }
}

// ---------------- K2: ux[dir][g][row] = m_matvec(Wih_dir[g], p[row]) ----------------
// grid 1334*6, block 256
__global__ __launch_bounds__(256) void k2(const float* __restrict__ p,
                                          const float* __restrict__ wih_f,
                                          const float* __restrict__ wih_b,
                                          float* __restrict__ ux) {
  __shared__ float pt[24][104];
  __shared__ float wt[100][108];
  __shared__ float alx[24];
  int bx = blockIdx.x; int tile = bx / 6; int combo = bx % 6;
  int dir = combo / 3, g = combo % 3;
  int row0 = tile * 24; int nrows = min(24, 32000 - row0);
  int t = threadIdx.x;
  const float* W = (dir ? wih_b : wih_f) + g * 10000;
#pragma unroll
  for (int q = 0; q < 10; q++) {
    int idx = t + 256 * q;
    if (idx < 2400) {
      int r = idx / 100, c = idx % 100;
      pt[r][c] = (r < nrows) ? p[(size_t)(row0 + r) * 100 + c] : 0.f;
    }
  }
#pragma unroll
  for (int q = 0; q < 40; q++) {
    int idx = t + 256 * q;
    if (idx < 10000) { int r = idx / 100, c = idx % 100; wt[r][c] = W[idx]; }
  }
  __syncthreads();
  int w = t >> 6, lane = t & 63;
  for (int r = w * 6; r < w * 6 + 6; r++) {
    float v0 = pt[r][lane], v1 = (lane < 36) ? pt[r][lane + 64] : 0.f;
    float s2 = wred(v0 * v0 + v1 * v1);
    if (lane == 0) {
      float xn = sqrtf(fmaxf(s2, MINF));
      alx[r] = artanh_c(xn) / xn;
    }
  }
  int rg = t / 25, og = t % 25; bool act = t < 200;
  float acc[3][4];
#pragma unroll
  for (int i = 0; i < 3; i++)
#pragma unroll
    for (int j = 0; j < 4; j++) acc[i][j] = 0.f;
  __syncthreads();
  if (act) {
#pragma unroll
    for (int k4 = 0; k4 < 25; k4++) {
      float4 pv[3], wv[4];
#pragma unroll
      for (int i = 0; i < 3; i++) pv[i] = *(const float4*)&pt[rg * 3 + i][k4 * 4];
#pragma unroll
      for (int j = 0; j < 4; j++) wv[j] = *(const float4*)&wt[og + 25 * j][k4 * 4];
#pragma unroll
      for (int i = 0; i < 3; i++)
#pragma unroll
        for (int j = 0; j < 4; j++)
          acc[i][j] += pv[i].x * wv[j].x + pv[i].y * wv[j].y + pv[i].z * wv[j].z + pv[i].w * wv[j].w;
    }
  }
  __syncthreads();
  if (act) {
#pragma unroll
    for (int i = 0; i < 3; i++)
#pragma unroll
      for (int j = 0; j < 4; j++) pt[rg * 3 + i][og + 25 * j] = acc[i][j];
  }
  __syncthreads();
  for (int r = w * 6; r < w * 6 + 6; r++) {
    if (r >= nrows) continue;
    float m0 = pt[r][lane], m1 = (lane < 36) ? pt[r][lane + 64] : 0.f;
    float s2 = wred(m0 * m0 + m1 * m1);
    float mxn = sqrtf(fmaxf(s2, MINF));
    float sc = tanhf(mxn * alx[r]) / mxn;
    float* dst = ux + ((size_t)(dir * 3 + g) * 32000 + row0 + r) * 100;
    dst[lane] = sc * m0;
    if (lane < 36) dst[lane + 64] = sc * m1;
  }
}

// ---------------- K3: sequential Mobius GRU ----------------
// unroll capped at 5: full 25x unroll holds ~100 VGPRs of float4 loads in
// flight and (at the old 64-VGPR cap) spilled ~7.7 GB/dispatch to scratch.
__device__ __forceinline__ void mv100(const float* __restrict__ Wg, const float* __restrict__ hrow,
                                      float* __restrict__ out, int lane) {
  const float4* W4 = (const float4*)Wg;
  const float4* h4 = (const float4*)hrow;
  float4 a0 = {0, 0, 0, 0}, a1 = {0, 0, 0, 0};
#pragma unroll 5
  for (int k4 = 0; k4 < 25; k4++) {
    float4 hv = h4[k4];
    float4 w0 = W4[k4 * 100 + lane];
    a0.x += w0.x * hv.x; a0.y += w0.y * hv.y; a0.z += w0.z * hv.z; a0.w += w0.w * hv.w;
    if (lane < 36) {
      float4 w1 = W4[k4 * 100 + lane + 64];
      a1.x += w1.x * hv.x; a1.y += w1.y * hv.y; a1.z += w1.z * hv.z; a1.w += w1.w * hv.w;
    }
  }
  out[lane] = a0.x + a0.y + a0.z + a0.w;
  if (lane < 36) out[64 + lane] = a1.x + a1.y + a1.z + a1.w;
}

// one_transform without bias-free parts: c = m_add(m_add(gamma*mv, ux), b)
__device__ __forceinline__ void onetrans(const float* __restrict__ mv, float ux0, float ux1,
                                         float alphax, float b_0, float b_1, float nb2, int lane,
                                         float& c0, float& c1) {
  float m0 = mv[lane];
  float m1 = (lane < 36) ? mv[64 + lane] : 0.f;
  float A = wred(m0 * m0 + m1 * m1);
  float B = wred(m0 * ux0 + m1 * ux1);
  float C = wred(ux0 * ux0 + ux1 * ux1);
  float mxn = sqrtf(fmaxf(A, MINF));
  float gam = tanhf(mxn * alphax) / mxn;
  float x2 = gam * gam * A, y2 = C, xy = gam * B;
  float rd = 1.f / fmaxf(1.f + 2.f * xy + x2 * y2, MINF);
  float cA = (1.f + 2.f * xy + y2) * gam * rd, cB = (1.f - x2) * rd;
  float a0 = cA * m0 + cB * ux0, a1 = cA * m1 + cB * ux1;
  float D = wred(a0 * a0 + a1 * a1);
  float E = wred(a0 * b_0 + a1 * b_1);
  float r2 = 1.f / fmaxf(1.f + 2.f * E + D * nb2, MINF);
  float t1 = (1.f + 2.f * E + nb2) * r2, t2 = (1.f - D) * r2;
  c0 = t1 * a0 + t2 * b_0;
  c1 = t1 * a1 + t2 * b_1;
}

// grid 256 (32 groups x 8 row-chunks), block 1024, dyn LDS 149120 B
// __launch_bounds__(1024, 4): 4 waves/EU = 16 waves = the single LDS-limited
// block/CU; raises the VGPR cap 64 -> 128 (64 caused massive scratch spill).
__global__ __launch_bounds__(1024, 4) void k3(const float* __restrict__ ux,
                                              const float* __restrict__ wt4,
                                              const float* __restrict__ bias_f,
                                              const float* __restrict__ bias_b,
                                              float* __restrict__ f) {
  extern __shared__ float lds[];
  float* Wlds = lds;                 // 30000
  float* mvl = lds + 30000;          // 13*3*112
  float* hl = mvl + 13 * 3 * 112;    // 13*112
  float* rhl = hl + 13 * 112;        // 13*112
  int t = threadIdx.x; int w = t >> 6; int lane = t & 63;
  int bx = blockIdx.x;
  int grp = bx >> 3; int blki = bx & 7;
  int n = grp >> 1; int dir = grp & 1;
  int b0 = blki * 13; int nrows = min(13, 100 - b0);
  const float* bias = dir ? bias_b : bias_f;
  const float* wsrc = wt4 + dir * 30000;
#pragma unroll
  for (int q = 0; q < 30; q++) { int idx = t + 1024 * q; if (idx < 30000) Wlds[idx] = wsrc[idx]; }
#pragma unroll
  for (int q = 0; q < 2; q++) { int idx = t + 1024 * q; if (idx < 13 * 112) hl[idx] = 0.f; }
  __syncthreads();

  int row = w; bool erow = (w < nrows);
  int b = b0 + row;
  float nh2 = 0.f, h0 = 0.f, h1 = 0.f;
  float bz0 = 0, bz1 = 0, br0 = 0, br1 = 0, bh0 = 0, bh1 = 0, nbz2 = 0, nbr2 = 0, nbh2 = 0;
  if (erow) {
    br0 = bias[lane];        if (lane < 36) br1 = bias[64 + lane];
    bh0 = bias[100 + lane];  if (lane < 36) bh1 = bias[164 + lane];
    bz0 = bias[200 + lane];  if (lane < 36) bz1 = bias[264 + lane];
    nbr2 = wred(br0 * br0 + br1 * br1);
    nbh2 = wred(bh0 * bh0 + bh1 * bh1);
    nbz2 = wred(bz0 * bz0 + bz1 * bz1);
  }
  for (int s = 0; s < 20; s++) {
    // M1: matvecs for z (g=2) and r (g=0) gates, distributed to all 16 waves
    for (int ti = w; ti < nrows * 2; ti += 16) {
      int mrow = ti >> 1; int g = (ti & 1) ? 0 : 2;
      mv100(Wlds + g * 10000, hl + mrow * 112, mvl + (mrow * 3 + g) * 112, lane);
    }
    __syncthreads();
    float z0 = 0, z1 = 0, uxh0 = 0, uxh1 = 0, nrh2 = 0;
    if (erow) {
      int l = dir ? (1999 - (s * 100 + b)) : (s * 100 + b);
      size_t rowg = (size_t)n * 2000 + l;
      const float* uxz = ux + ((size_t)(dir * 3 + 2) * 32000 + rowg) * 100;
      const float* uxr = ux + ((size_t)(dir * 3 + 0) * 32000 + rowg) * 100;
      const float* uxh = ux + ((size_t)(dir * 3 + 1) * 32000 + rowg) * 100;
      float uz0 = uxz[lane], uz1 = (lane < 36) ? uxz[lane + 64] : 0.f;
      float ur0 = uxr[lane], ur1 = (lane < 36) ? uxr[lane + 64] : 0.f;
      uxh0 = uxh[lane]; uxh1 = (lane < 36) ? uxh[lane + 64] : 0.f;
      float xnh = sqrtf(fmaxf(nh2, MINF));
      float alphah = artanh_c(xnh) / xnh;
      float cz0, cz1, cr0, cr1;
      onetrans(mvl + (row * 3 + 2) * 112, uz0, uz1, alphah, bz0, bz1, nbz2, lane, cz0, cz1);
      onetrans(mvl + (row * 3 + 0) * 112, ur0, ur1, alphah, br0, br1, nbr2, lane, cr0, cr1);
      float Fz = wred(cz0 * cz0 + cz1 * cz1);
      float cnz = sqrtf(fmaxf(Fz, MINF)); float lgz = artanh_c(cnz) / cnz;
      z0 = sigm(lgz * cz0); z1 = sigm(lgz * cz1);
      float Fr = wred(cr0 * cr0 + cr1 * cr1);
      float cnr = sqrtf(fmaxf(Fr, MINF)); float lgr = artanh_c(cnr) / cnr;
      float r0 = sigm(lgr * cr0), r1 = sigm(lgr * cr1);
      // rh = m_pw(r, h)
      float mx0 = r0 * h0, mx1 = r1 * h1;
      float G = wred(mx0 * mx0 + mx1 * mx1);
      float mxnr = sqrtf(fmaxf(G, MINF));
      float srh = tanhf(mxnr * alphah) / mxnr;
      rhl[row * 112 + lane] = srh * mx0;
      if (lane < 36) rhl[row * 112 + lane + 64] = srh * mx1;
      nrh2 = srh * srh * G;
      // M2 (own row): htil matvec — same wave wrote rhl, no barrier needed
      mv100(Wlds + 1 * 10000, rhl + row * 112, mvl + (row * 3 + 1) * 112, lane);
      // E2
      float xnrh = sqrtf(fmaxf(nrh2, MINF));
      float alpharh = artanh_c(xnrh) / xnrh;
      float ct0, ct1;
      onetrans(mvl + (row * 3 + 1) * 112, uxh0, uxh1, alpharh, bh0, bh1, nbh2, lane, ct0, ct1);
      // d = m_add(-h, htil)
      float T = wred(ct0 * ct0 + ct1 * ct1);
      float U = wred(h0 * ct0 + h1 * ct1);
      float rd = 1.f / fmaxf(1.f - 2.f * U + nh2 * T, MINF);
      float cA = (1.f - 2.f * U + T) * rd, cB = (1.f - nh2) * rd;
      float d0 = -cA * h0 + cB * ct0, d1 = -cA * h1 + cB * ct1;
      // pw = m_pw(z, d)
      float zd0 = z0 * d0, zd1 = z1 * d1;
      float nd2 = wred(d0 * d0 + d1 * d1);
      float P = wred(zd0 * zd0 + zd1 * zd1);
      float Q = wred(h0 * zd0 + h1 * zd1);
      float xnd = sqrtf(fmaxf(nd2, MINF));
      float mxnp = sqrtf(fmaxf(P, MINF));
      float sp = tanhf(mxnp * artanh_c(xnd) / xnd) / mxnp;
      float pw0 = sp * zd0, pw1 = sp * zd1;
      float y2 = sp * sp * P, xy = sp * Q;
      float r3 = 1.f / fmaxf(1.f + 2.f * xy + nh2 * y2, MINF);
      float hn0 = (1.f + 2.f * xy + y2) * r3 * h0 + (1.f - nh2) * r3 * pw0;
      float hn1 = (1.f + 2.f * xy + y2) * r3 * h1 + (1.f - nh2) * r3 * pw1;
      nh2 = wred(hn0 * hn0 + hn1 * hn1);
      h0 = hn0; h1 = hn1;
      hl[row * 112 + lane] = hn0;
      if (lane < 36) hl[row * 112 + lane + 64] = hn1;
      float* fd = f + (((size_t)n * 20 + s) * 100 + b) * 200 + dir * 100;
      fd[lane] = hn0;
      if (lane < 36) fd[lane + 64] = hn1;
    }
    __syncthreads();
  }
}

// ---------------- K4a: MobiusLinear(Wp) + lorentz logits a, gamma ----------------
// grid 1334, block 256
__global__ __launch_bounds__(256) void k4a(const float* __restrict__ f, const float* __restrict__ Wp,
                                           const float* __restrict__ bp, const float* __restrict__ cl,
                                           const float* __restrict__ beta_p,
                                           float* __restrict__ a_out, float* __restrict__ g_out) {
  __shared__ float ft[24][208];
  __shared__ float wt[200][44];
  __shared__ float alx[24];
  __shared__ float nf2s[24];
  int bx = blockIdx.x; int row0 = bx * 24; int nrows = min(24, 32000 - row0);
  int t = threadIdx.x; int w = t >> 6; int lane = t & 63;
#pragma unroll
  for (int q = 0; q < 19; q++) {
    int idx = t + 256 * q;
    if (idx < 4800) {
      int r = idx / 200, c = idx % 200;
      ft[r][c] = (r < nrows) ? f[(size_t)(row0 + r) * 200 + c] : 0.f;
    }
  }
  __syncthreads();
  for (int r = w * 6; r < w * 6 + 6; r++) {
    float v0 = ft[r][lane], v1 = ft[r][lane + 64], v2 = ft[r][lane + 128];
    float v3 = (lane < 8) ? ft[r][lane + 192] : 0.f;
    float s2 = wred(v0 * v0 + v1 * v1 + v2 * v2 + v3 * v3);
    if (lane == 0) {
      nf2s[r] = s2;
      float xn = sqrtf(fmaxf(s2, MINF));
      alx[r] = artanh_c(xn) / xn;
    }
  }
  int rg = t / 25, og = t % 25; bool act = t < 200;
  float acc[3][8];
#pragma unroll
  for (int i = 0; i < 3; i++)
#pragma unroll
    for (int j = 0; j < 8; j++) acc[i][j] = 0.f;
  for (int kc = 0; kc < 5; kc++) {
    int k0 = kc * 40;
    __syncthreads();
#pragma unroll
    for (int q = 0; q < 32; q++) {
      int idx = t + 256 * q;
      if (idx < 8000) { int r = idx / 40, c = idx % 40; wt[r][c] = Wp[(size_t)r * 200 + k0 + c]; }
    }
    __syncthreads();
    if (act) {
#pragma unroll
      for (int k4 = 0; k4 < 10; k4++) {
        float4 pv[3];
#pragma unroll
        for (int i = 0; i < 3; i++) pv[i] = *(const float4*)&ft[rg * 3 + i][k0 + k4 * 4];
#pragma unroll
        for (int j = 0; j < 8; j++) {
          float4 wv = *(const float4*)&wt[og + 25 * j][k4 * 4];
#pragma unroll
          for (int i = 0; i < 3; i++)
            acc[i][j] += pv[i].x * wv.x + pv[i].y * wv.y + pv[i].z * wv.z + pv[i].w * wv.w;
        }
      }
    }
  }
  __syncthreads();
  if (act) {
#pragma unroll
    for (int i = 0; i < 3; i++)
#pragma unroll
      for (int j = 0; j < 8; j++) ft[rg * 3 + i][og + 25 * j] = acc[i][j];
  }
  __syncthreads();
  float beta = beta_p[0];
  float c200 = cl[200];
  float b_0 = bp[lane], b_1 = bp[lane + 64], b_2 = bp[lane + 128];
  float b_3 = (lane < 8) ? bp[lane + 192] : 0.f;
  float c_0 = cl[lane], c_1 = cl[lane + 64], c_2 = cl[lane + 128];
  float c_3 = (lane < 8) ? cl[lane + 192] : 0.f;
  float nbp2 = wred(b_0 * b_0 + b_1 * b_1 + b_2 * b_2 + b_3 * b_3);
  for (int r = w * 6; r < w * 6 + 6; r++) {
    if (r >= nrows) continue;
    float m0 = ft[r][lane], m1 = ft[r][lane + 64], m2 = ft[r][lane + 128];
    float m3 = (lane < 8) ? ft[r][lane + 192] : 0.f;
    float A = wred(m0 * m0 + m1 * m1 + m2 * m2 + m3 * m3);
    float B = wred(m0 * b_0 + m1 * b_1 + m2 * b_2 + m3 * b_3);
    float mxn = sqrtf(fmaxf(A, MINF));
    float gam = tanhf(mxn * alx[r]) / mxn;
    float x2 = gam * gam * A, y2 = nbp2, xy = gam * B;
    float rd = 1.f / fmaxf(1.f + 2.f * xy + x2 * y2, MINF);
    float cA = (1.f + 2.f * xy + y2) * gam * rd, cB = (1.f - x2) * rd;
    float a0 = cA * m0 + cB * b_0, a1 = cA * m1 + cB * b_1;
    float a2 = cA * m2 + cB * b_2, a3 = cA * m3 + cB * b_3;
    float r2 = wred(a0 * a0 + a1 * a1 + a2 * a2 + a3 * a3);
    float dc = wred(a0 * c_0 + a1 * c_1 + a2 * c_2 + a3 * c_3);
    float pm = (-2.f * dc + (1.f + r2) * c200) / (1.f - r2 + EPSF);
    pm = fminf(fmaxf(pm, 1.f + EPSF), 1e16f);
    float av = -beta * arcosh_(pm) - 1.f;
    float nf2 = nf2s[r];
    float invg = 1.f - 4.f * nf2 / ((1.f + nf2) * (1.f + nf2));
    invg = fminf(fmaxf(invg, EPSF), 1.f - EPSF);
    float gv = fminf(fmaxf(1.f / sqrtf(invg), 1.f + EPSF), 1e16f);
    if (lane == 0) { a_out[row0 + r] = av; g_out[row0 + r] = gv; }
  }
}

// ---------------- K4b: per-sample softmax weights ----------------
// grid 16, block 256
__global__ __launch_bounds__(256) void k4b(const float* __restrict__ a_in,
                                           const float* __restrict__ g_in,
                                           float* __restrict__ wgt) {
  __shared__ float rl[2000];
  __shared__ float sred[4];
  __shared__ float rsinv[100];
  int n = blockIdx.x; int t = threadIdx.x;
  int w = t >> 6, lane = t & 63;
  const float* ap = a_in + n * 2000;
  const float* gp = g_in + n * 2000;
  float av[8]; float am = -1e30f;
#pragma unroll
  for (int q = 0; q < 8; q++) {
    int i = t + 256 * q;
    av[q] = (i < 2000) ? ap[i] : -1e30f;
    am = fmaxf(am, av[q]);
  }
  am = wredmax(am);
  if (lane == 0) sred[w] = am;
  __syncthreads();
  float amax = fmaxf(fmaxf(sred[0], sred[1]), fmaxf(sred[2], sred[3]));
#pragma unroll
  for (int q = 0; q < 8; q++) {
    int i = t + 256 * q;
    if (i < 2000) rl[i] = expf(av[q] - amax) * gp[i];
  }
  __syncthreads();
  if (t < 100) {
    float ssum = 0.f;
#pragma unroll
    for (int s = 0; s < 20; s++) ssum += rl[s * 100 + t];
    rsinv[t] = 1.f / ssum;
  }
  __syncthreads();
#pragma unroll
  for (int q = 0; q < 8; q++) {
    int i = t + 256 * q;
    if (i < 2000) wgt[n * 2000 + i] = rl[i] * rsinv[i % 100];
  }
}

// ---------------- K4c: klein aggregation + final GEMM W2 ----------------
// grid 320 (n,s), block 256
__global__ __launch_bounds__(256) void k4c(const float* __restrict__ f, const float* __restrict__ wgt,
                                           const float* __restrict__ W2, const float* __restrict__ b2,
                                           float* __restrict__ out) {
  __shared__ float cw[100];
  __shared__ float ol[200];
  __shared__ float sred[4];
  int bx = blockIdx.x; int n = bx / 20, s = bx % 20;
  int t = threadIdx.x; int w = t >> 6; int lane = t & 63;
  const float* fb = f + ((size_t)n * 20 + s) * 100 * 200;
  for (int bi = w * 25; bi < w * 25 + 25; bi++) {
    const float* fr = fb + bi * 200;
    float v0 = fr[lane], v1 = fr[lane + 64], v2 = fr[lane + 128];
    float v3 = (lane < 8) ? fr[lane + 192] : 0.f;
    float s2 = wred(v0 * v0 + v1 * v1 + v2 * v2 + v3 * v3);
    if (lane == 0) cw[bi] = wgt[n * 2000 + s * 100 + bi] * 2.f / (1.f + s2);
  }
  __syncthreads();
  float o = 0.f;
  if (t < 200) {
    for (int bi = 0; bi < 100; bi++) o += cw[bi] * fb[bi * 200 + t];
  }
  float ps = (t < 200) ? o * o : 0.f;
  ps = wred(ps);
  if (lane == 0) sred[w] = ps;
  __syncthreads();
  float no2 = sred[0] + sred[1] + sred[2] + sred[3];
  float denom = 1.f + sqrtf(1.f + no2);
  if (t < 200) ol[t] = o / denom;
  __syncthreads();
  const float4* ol4 = (const float4*)ol;
#pragma unroll
  for (int jj = 0; jj < 3; jj++) {
    int j = t + 256 * jj;
    const float4* wrow = (const float4*)(W2 + (size_t)j * 200);
    float a0 = 0, a1 = 0, a2 = 0, a3 = 0;
    for (int k4 = 0; k4 < 50; k4++) {
      float4 wv = wrow[k4]; float4 ov = ol4[k4];
      a0 += wv.x * ov.x; a1 += wv.y * ov.y; a2 += wv.z * ov.z; a3 += wv.w * ov.w;
    }
    out[((size_t)n * 20 + s) * 768 + j] = a0 + a1 + a2 + a3 + b2[j];
  }
}

extern "C" void kernel_launch(void* const* d_in, const int* in_sizes, int n_in,
                              void* d_out, int out_size, void* d_ws, size_t ws_size,
                              hipStream_t stream) {
  const float* x_     = (const float*)d_in[0];
  const float* W1     = (const float*)d_in[1];
  const float* b1     = (const float*)d_in[2];
  const float* W2     = (const float*)d_in[3];
  const float* b2     = (const float*)d_in[4];
  const float* Wih_f  = (const float*)d_in[5];
  const float* Whh_f  = (const float*)d_in[6];
  const float* bias_f = (const float*)d_in[7];
  const float* Wih_b  = (const float*)d_in[8];
  const float* Whh_b  = (const float*)d_in[9];
  const float* bias_b = (const float*)d_in[10];
  const float* centroid = (const float*)d_in[11];
  const float* Wp     = (const float*)d_in[12];
  const float* bp     = (const float*)d_in[13];
  const float* beta   = (const float*)d_in[14];
  float* out = (float*)d_out;
  float* ws = (float*)d_ws;
  float* p   = ws + OFF_P;
  float* ux  = ws + OFF_UX;
  float* wt4 = ws + OFF_WT4;
  float* f   = ws + OFF_F;
  float* cl  = ws + OFF_CL;
  float* aa  = ws + OFF_A;
  float* gg  = ws + OFF_G;
  float* wg  = ws + OFF_WGT;

  (void)hipFuncSetAttribute(reinterpret_cast<const void*>(k3),
                            hipFuncAttributeMaxDynamicSharedMemorySize, K3_LDS_BYTES);

  k0_pack<<<235, 256, 0, stream>>>(Whh_f, Whh_b, wt4);
  k0_cl<<<1, 256, 0, stream>>>(centroid, cl);
  k1<<<800, 256, 0, stream>>>(x_, W1, b1, p);
  k2<<<8004, 256, 0, stream>>>(p, Wih_f, Wih_b, ux);
  k3<<<256, 1024, K3_LDS_BYTES, stream>>>(ux, wt4, bias_f, bias_b, f);
  k4a<<<1334, 256, 0, stream>>>(f, Wp, bp, cl, beta, aa, gg);
  k4b<<<16, 256, 0, stream>>>(aa, gg, wg);
  k4c<<<320, 256, 0, stream>>>(f, wg, W2, b2, out);
}

// Round 3
// 1170.634 us; speedup vs baseline: 2.6941x; 1.4304x over previous
//
#include <hip/hip_runtime.h>
#include <hip/hip_bf16.h>

#define MINF 1e-15f
#define EPSF 1e-6f

// ---------- workspace layout (floats) ----------
#define OFF_P    0u            // 16*2000*100      = 3,200,000
#define OFF_UX   3200000u      // 2*3*32000*100    = 19,200,000
#define OFF_WT4  22400000u     // 2*3*25*100*4     = 60,000
#define OFF_F    22460000u     // 16*20*100*200    = 6,400,000
#define OFF_CL   28860000u     // 201 (pad 256)
#define OFF_A    28860256u     // 32000
#define OFF_G    28892256u     // 32000
#define OFF_WGT  28924256u     // 32000
// wi4 (60000) and w1p (76800) live in the first floats of the f region:
// k0_pack writes them, k1/k2 consume them, then k3 overwrites f. No extra ws.
#define OFF_WI4  OFF_F
#define OFF_W1P  (OFF_F + 60000u)

#define K3_LDS_BYTES 149120    // (30000 + 13*3*112 + 13*112 + 13*112) * 4
#define K2_LDS_BYTES ((3200 + 64*26)*16 + 64*4)   // W 51200 + p 26624 + alx 256 = 78080

__device__ __forceinline__ float wred(float v) {
#pragma unroll
  for (int m = 32; m > 0; m >>= 1) v += __shfl_xor(v, m, 64);
  return v;
}
__device__ __forceinline__ float wredmax(float v) {
#pragma unroll
  for (int m = 32; m > 0; m >>= 1) v = fmaxf(v, __shfl_xor(v, m, 64));
  return v;
}
__device__ __forceinline__ float artanh_c(float x) {
  x = fminf(x, 1.f - 1e-7f);
  return 0.5f * (log1pf(x) - log1pf(-x));
}
__device__ __forceinline__ float arcosh_(float x) {
  return logf(x) + log1pf(sqrtf(fmaxf(x * x - 1.f + EPSF, 0.f)) / x);
}
__device__ __forceinline__ float sigm(float x) { return 1.f / (1.f + expf(-x)); }

// ---------------- K0a: pack weights into float4-friendly layouts ----------------
// Whh -> wt4 [dir][g][k4][j][4]        (for k3's mv100)
// Wih -> wi4 [combo][k4][c][4]         (for k2's GEMM; combo = dir*3+g)
// W1  -> w1p [k4][c][4], k4 in [0,192) (for k1's GEMM)
__global__ void k0_pack(const float* __restrict__ whh_f, const float* __restrict__ whh_b,
                        const float* __restrict__ wih_f, const float* __restrict__ wih_b,
                        const float* __restrict__ W1,
                        float* __restrict__ wt4, float* __restrict__ wi4,
                        float* __restrict__ w1p) {
  int idx = blockIdx.x * 256 + threadIdx.x;
  if (idx < 60000) {
    int kk = idx & 3; int t = idx >> 2;
    int j = t % 100; t /= 100;
    int k4 = t % 25; t /= 25;
    int g = t % 3; int dir = t / 3;
    const float* src = dir ? whh_b : whh_f;
    wt4[idx] = src[g * 10000 + j * 100 + k4 * 4 + kk];
  } else if (idx < 120000) {
    int i2 = idx - 60000;
    int kk = i2 & 3; int t = i2 >> 2;
    int c = t % 100; t /= 100;
    int k4 = t % 25; t /= 25;
    int g = t % 3; int dir = t / 3;
    const float* src = dir ? wih_b : wih_f;
    wi4[i2] = src[g * 10000 + c * 100 + k4 * 4 + kk];
  } else if (idx < 196800) {
    int i2 = idx - 120000;
    int kk = i2 & 3; int t = i2 >> 2;
    int c = t % 100; int k4 = t / 100;
    w1p[i2] = W1[c * 768 + k4 * 4 + kk];
  }
}

// ---------------- K0b: lorentz_activation(centroid) -> cl[201] ----------------
__global__ void k0_cl(const float* __restrict__ centroid, float* __restrict__ cl) {
  __shared__ float sred[4];
  int t = threadIdx.x;
  float v = (t < 200) ? centroid[t] : 0.f;
  float ps = wred(v * v);
  if ((t & 63) == 0) sred[t >> 6] = ps;
  __syncthreads();
  float r = sqrtf(sred[0] + sred[1] + sred[2] + sred[3]);
  if (t < 200) cl[t] = v / r * sinhf(r);
  if (t == 0) cl[200] = coshf(r);
}

// ---------------- K1: klein(x_) @ W1^T + b1, poincare project -> p ----------------
// Register-tiled GEMM: 64 rows x 128 cols (100 live) per block, K=768 in 12 chunks.
// Thread = (rg 0..7, cg 0..31); owns 8 rows x 4 cols (cols cg+32j). grid 500.
__global__ __launch_bounds__(256, 2) void k1(const float* __restrict__ x_,
                                             const float* __restrict__ w1p,
                                             const float* __restrict__ b1,
                                             float* __restrict__ p) {
  __shared__ float4 wl[16 * 128];   // 32 KB: W chunk [16 k4][128 c] (c>=100 zero)
  __shared__ float4 xl[64 * 16];    // 16 KB: x chunk [64 r][16 k4]
  __shared__ float ns[64];
  __shared__ float sscale[64];
  int t = threadIdx.x;
  int row0 = blockIdx.x * 64;
  int cg = t & 31, rg = t >> 5;
  const float4* wsrc = (const float4*)w1p;
  float nacc[4] = {0, 0, 0, 0};
  float acc[8][4] = {};
  for (int kc = 0; kc < 12; kc++) {
    int k0f4 = kc * 16;
    __syncthreads();   // protect wl/xl from previous iteration's readers
#pragma unroll
    for (int q = 0; q < 4; q++) {
      int idx = t + 256 * q;          // < 1024
      int r = idx >> 4, c4 = idx & 15;
      float4 v = *(const float4*)(x_ + (size_t)(row0 + r) * 768 + (size_t)(k0f4 + c4) * 4);
      xl[idx] = v;
      nacc[q] += v.x * v.x + v.y * v.y + v.z * v.z + v.w * v.w;
    }
#pragma unroll
    for (int q = 0; q < 8; q++) {
      int idx = t + 256 * q;          // < 2048
      int k4 = idx >> 7, c = idx & 127;
      float4 v = {0, 0, 0, 0};
      if (c < 100) v = wsrc[(size_t)(k0f4 + k4) * 100 + c];
      wl[idx] = v;
    }
    __syncthreads();
#pragma unroll 4
    for (int k4 = 0; k4 < 16; k4++) {
      float4 wv[4];
#pragma unroll
      for (int j = 0; j < 4; j++) wv[j] = wl[k4 * 128 + cg + 32 * j];
#pragma unroll
      for (int i = 0; i < 8; i++) {
        float4 pv = xl[(rg * 8 + i) * 16 + k4];
#pragma unroll
        for (int j = 0; j < 4; j++)
          acc[i][j] += pv.x * wv[j].x + pv.y * wv[j].y + pv.z * wv[j].z + pv.w * wv[j].w;
      }
    }
  }
  __syncthreads();
  // row norms of x: each row's 768 elems were staged by the 16 threads t>>4==r%16
#pragma unroll
  for (int q = 0; q < 4; q++) {
    float v = nacc[q];
#pragma unroll
    for (int m = 8; m > 0; m >>= 1) v += __shfl_xor(v, m, 64);
    if ((t & 15) == 0) ns[(t >> 4) + 16 * q] = v;
  }
  __syncthreads();
  if (t < 64) {
    float rr = sqrtf(fmaxf(ns[t], MINF));
    sscale[t] = tanhf(rr) / rr;   // klein factor tanh(|x|)/|x|
  }
  __syncthreads();
  float bcol[4];
#pragma unroll
  for (int j = 0; j < 4; j++) {
    int col = cg + 32 * j;
    bcol[j] = (col < 100) ? b1[col] : 0.f;
  }
#pragma unroll
  for (int i = 0; i < 8; i++) {
    int r = rg * 8 + i;
    float s = sscale[r];
    float hv[4]; float ss = 0.f;
#pragma unroll
    for (int j = 0; j < 4; j++) {
      int col = cg + 32 * j;
      hv[j] = (col < 100) ? (s * acc[i][j] + bcol[j]) : 0.f;
      ss += hv[j] * hv[j];
    }
#pragma unroll
    for (int m = 16; m > 0; m >>= 1) ss += __shfl_xor(ss, m, 64);
    float inv = 1.f / sqrtf(1.f + ss);   // poincare projection
    float* prow = p + (size_t)(row0 + r) * 100;
#pragma unroll
    for (int j = 0; j < 4; j++) {
      int col = cg + 32 * j;
      if (col < 100) prow[col] = hv[j] * inv;
    }
  }
}

// ---------------- K2: ux[combo][row] = m_matvec(Wih_combo, p[row]) ----------------
// Register-tiled GEMM: 64 rows x 1 combo per block; K=100 (25 float4).
// grid 3000 (tile-major: adjacent blocks share W in L2). dyn LDS 78080 B.
__global__ __launch_bounds__(256, 2) void k2(const float* __restrict__ p,
                                             const float* __restrict__ wi4,
                                             float* __restrict__ ux) {
  extern __shared__ float4 l4[];
  float4* wl = l4;                       // 3200 f4: [25 k4][128 c] (c>=100 zero)
  float4* pl = l4 + 3200;                // 64*26 f4: [64 r][25 k4 + pad]
  float* alx = (float*)(l4 + 3200 + 64 * 26);  // 64
  int t = threadIdx.x;
  int bx = blockIdx.x;
  int combo = bx / 500, tile = bx % 500;
  int row0 = tile * 64;
  int cg = t & 31, rg = t >> 5;
  const float4* wsrc = (const float4*)wi4 + (size_t)combo * 2500;
#pragma unroll
  for (int q = 0; q < 13; q++) {
    int idx = t + 256 * q;
    if (idx < 3200) {
      int k4 = idx >> 7, c = idx & 127;
      float4 v = {0, 0, 0, 0};
      if (c < 100) v = wsrc[k4 * 100 + c];
      wl[idx] = v;
    }
  }
  const float4* psrc = (const float4*)(p + (size_t)row0 * 100);
#pragma unroll
  for (int q = 0; q < 7; q++) {
    int idx = t + 256 * q;
    if (idx < 1600) {
      int r = idx / 25, c4 = idx % 25;
      pl[r * 26 + c4] = psrc[idx];
    }
  }
  __syncthreads();
  {
    int w = t >> 6, lane = t & 63;
    const float* pf = (const float*)pl;
    for (int r = w * 16; r < w * 16 + 16; r++) {
      float v0 = pf[r * 104 + lane];
      float v1 = (lane < 36) ? pf[r * 104 + 64 + lane] : 0.f;
      float s2 = wred(v0 * v0 + v1 * v1);
      if (lane == 0) {
        float xn = sqrtf(fmaxf(s2, MINF));
        alx[r] = artanh_c(xn) / xn;
      }
    }
  }
  __syncthreads();
  float acc[8][4] = {};
#pragma unroll 5
  for (int k4 = 0; k4 < 25; k4++) {
    float4 wv[4];
#pragma unroll
    for (int j = 0; j < 4; j++) wv[j] = wl[k4 * 128 + cg + 32 * j];
#pragma unroll
    for (int i = 0; i < 8; i++) {
      float4 pv = pl[(rg * 8 + i) * 26 + k4];
#pragma unroll
      for (int j = 0; j < 4; j++)
        acc[i][j] += pv.x * wv[j].x + pv.y * wv[j].y + pv.z * wv[j].z + pv.w * wv[j].w;
    }
  }
#pragma unroll
  for (int i = 0; i < 8; i++) {
    int r = rg * 8 + i;
    float ss = acc[i][0] * acc[i][0] + acc[i][1] * acc[i][1] +
               acc[i][2] * acc[i][2] + acc[i][3] * acc[i][3];
#pragma unroll
    for (int m = 16; m > 0; m >>= 1) ss += __shfl_xor(ss, m, 64);
    float mxn = sqrtf(fmaxf(ss, MINF));
    float sc = tanhf(mxn * alx[r]) / mxn;
    float* dst = ux + ((size_t)combo * 32000 + row0 + r) * 100;
#pragma unroll
    for (int j = 0; j < 4; j++) {
      int col = cg + 32 * j;
      if (col < 100) dst[col] = sc * acc[i][j];
    }
  }
}

// ---------------- K3: sequential Mobius GRU ----------------
// unroll capped at 5: full 25x unroll holds ~100 VGPRs of float4 loads in
// flight and (at the old 64-VGPR cap) spilled ~7.7 GB/dispatch to scratch.
__device__ __forceinline__ void mv100(const float* __restrict__ Wg, const float* __restrict__ hrow,
                                      float* __restrict__ out, int lane) {
  const float4* W4 = (const float4*)Wg;
  const float4* h4 = (const float4*)hrow;
  float4 a0 = {0, 0, 0, 0}, a1 = {0, 0, 0, 0};
#pragma unroll 5
  for (int k4 = 0; k4 < 25; k4++) {
    float4 hv = h4[k4];
    float4 w0 = W4[k4 * 100 + lane];
    a0.x += w0.x * hv.x; a0.y += w0.y * hv.y; a0.z += w0.z * hv.z; a0.w += w0.w * hv.w;
    if (lane < 36) {
      float4 w1 = W4[k4 * 100 + lane + 64];
      a1.x += w1.x * hv.x; a1.y += w1.y * hv.y; a1.z += w1.z * hv.z; a1.w += w1.w * hv.w;
    }
  }
  out[lane] = a0.x + a0.y + a0.z + a0.w;
  if (lane < 36) out[64 + lane] = a1.x + a1.y + a1.z + a1.w;
}

// one_transform without bias-free parts: c = m_add(m_add(gamma*mv, ux), b)
__device__ __forceinline__ void onetrans(const float* __restrict__ mv, float ux0, float ux1,
                                         float alphax, float b_0, float b_1, float nb2, int lane,
                                         float& c0, float& c1) {
  float m0 = mv[lane];
  float m1 = (lane < 36) ? mv[64 + lane] : 0.f;
  float A = wred(m0 * m0 + m1 * m1);
  float B = wred(m0 * ux0 + m1 * ux1);
  float C = wred(ux0 * ux0 + ux1 * ux1);
  float mxn = sqrtf(fmaxf(A, MINF));
  float gam = tanhf(mxn * alphax) / mxn;
  float x2 = gam * gam * A, y2 = C, xy = gam * B;
  float rd = 1.f / fmaxf(1.f + 2.f * xy + x2 * y2, MINF);
  float cA = (1.f + 2.f * xy + y2) * gam * rd, cB = (1.f - x2) * rd;
  float a0 = cA * m0 + cB * ux0, a1 = cA * m1 + cB * ux1;
  float D = wred(a0 * a0 + a1 * a1);
  float E = wred(a0 * b_0 + a1 * b_1);
  float r2 = 1.f / fmaxf(1.f + 2.f * E + D * nb2, MINF);
  float t1 = (1.f + 2.f * E + nb2) * r2, t2 = (1.f - D) * r2;
  c0 = t1 * a0 + t2 * b_0;
  c1 = t1 * a1 + t2 * b_1;
}

// grid 256 (32 groups x 8 row-chunks), block 1024, dyn LDS 149120 B
// __launch_bounds__(1024, 4): 4 waves/EU = 16 waves = the single LDS-limited
// block/CU; raises the VGPR cap 64 -> 128 (64 caused massive scratch spill).
__global__ __launch_bounds__(1024, 4) void k3(const float* __restrict__ ux,
                                              const float* __restrict__ wt4,
                                              const float* __restrict__ bias_f,
                                              const float* __restrict__ bias_b,
                                              float* __restrict__ f) {
  extern __shared__ float lds[];
  float* Wlds = lds;                 // 30000
  float* mvl = lds + 30000;          // 13*3*112
  float* hl = mvl + 13 * 3 * 112;    // 13*112
  float* rhl = hl + 13 * 112;        // 13*112
  int t = threadIdx.x; int w = t >> 6; int lane = t & 63;
  int bx = blockIdx.x;
  int grp = bx >> 3; int blki = bx & 7;
  int n = grp >> 1; int dir = grp & 1;
  int b0 = blki * 13; int nrows = min(13, 100 - b0);
  const float* bias = dir ? bias_b : bias_f;
  const float* wsrc = wt4 + dir * 30000;
#pragma unroll
  for (int q = 0; q < 30; q++) { int idx = t + 1024 * q; if (idx < 30000) Wlds[idx] = wsrc[idx]; }
#pragma unroll
  for (int q = 0; q < 2; q++) { int idx = t + 1024 * q; if (idx < 13 * 112) hl[idx] = 0.f; }
  __syncthreads();

  int row = w; bool erow = (w < nrows);
  int b = b0 + row;
  float nh2 = 0.f, h0 = 0.f, h1 = 0.f;
  float bz0 = 0, bz1 = 0, br0 = 0, br1 = 0, bh0 = 0, bh1 = 0, nbz2 = 0, nbr2 = 0, nbh2 = 0;
  if (erow) {
    br0 = bias[lane];        if (lane < 36) br1 = bias[64 + lane];
    bh0 = bias[100 + lane];  if (lane < 36) bh1 = bias[164 + lane];
    bz0 = bias[200 + lane];  if (lane < 36) bz1 = bias[264 + lane];
    nbr2 = wred(br0 * br0 + br1 * br1);
    nbh2 = wred(bh0 * bh0 + bh1 * bh1);
    nbz2 = wred(bz0 * bz0 + bz1 * bz1);
  }
  for (int s = 0; s < 20; s++) {
    // M1: matvecs for z (g=2) and r (g=0) gates, distributed to all 16 waves
    for (int ti = w; ti < nrows * 2; ti += 16) {
      int mrow = ti >> 1; int g = (ti & 1) ? 0 : 2;
      mv100(Wlds + g * 10000, hl + mrow * 112, mvl + (mrow * 3 + g) * 112, lane);
    }
    __syncthreads();
    float z0 = 0, z1 = 0, uxh0 = 0, uxh1 = 0, nrh2 = 0;
    if (erow) {
      int l = dir ? (1999 - (s * 100 + b)) : (s * 100 + b);
      size_t rowg = (size_t)n * 2000 + l;
      const float* uxz = ux + ((size_t)(dir * 3 + 2) * 32000 + rowg) * 100;
      const float* uxr = ux + ((size_t)(dir * 3 + 0) * 32000 + rowg) * 100;
      const float* uxh = ux + ((size_t)(dir * 3 + 1) * 32000 + rowg) * 100;
      float uz0 = uxz[lane], uz1 = (lane < 36) ? uxz[lane + 64] : 0.f;
      float ur0 = uxr[lane], ur1 = (lane < 36) ? uxr[lane + 64] : 0.f;
      uxh0 = uxh[lane]; uxh1 = (lane < 36) ? uxh[lane + 64] : 0.f;
      float xnh = sqrtf(fmaxf(nh2, MINF));
      float alphah = artanh_c(xnh) / xnh;
      float cz0, cz1, cr0, cr1;
      onetrans(mvl + (row * 3 + 2) * 112, uz0, uz1, alphah, bz0, bz1, nbz2, lane, cz0, cz1);
      onetrans(mvl + (row * 3 + 0) * 112, ur0, ur1, alphah, br0, br1, nbr2, lane, cr0, cr1);
      float Fz = wred(cz0 * cz0 + cz1 * cz1);
      float cnz = sqrtf(fmaxf(Fz, MINF)); float lgz = artanh_c(cnz) / cnz;
      z0 = sigm(lgz * cz0); z1 = sigm(lgz * cz1);
      float Fr = wred(cr0 * cr0 + cr1 * cr1);
      float cnr = sqrtf(fmaxf(Fr, MINF)); float lgr = artanh_c(cnr) / cnr;
      float r0 = sigm(lgr * cr0), r1 = sigm(lgr * cr1);
      // rh = m_pw(r, h)
      float mx0 = r0 * h0, mx1 = r1 * h1;
      float G = wred(mx0 * mx0 + mx1 * mx1);
      float mxnr = sqrtf(fmaxf(G, MINF));
      float srh = tanhf(mxnr * alphah) / mxnr;
      rhl[row * 112 + lane] = srh * mx0;
      if (lane < 36) rhl[row * 112 + lane + 64] = srh * mx1;
      nrh2 = srh * srh * G;
      // M2 (own row): htil matvec — same wave wrote rhl, no barrier needed
      mv100(Wlds + 1 * 10000, rhl + row * 112, mvl + (row * 3 + 1) * 112, lane);
      // E2
      float xnrh = sqrtf(fmaxf(nrh2, MINF));
      float alpharh = artanh_c(xnrh) / xnrh;
      float ct0, ct1;
      onetrans(mvl + (row * 3 + 1) * 112, uxh0, uxh1, alpharh, bh0, bh1, nbh2, lane, ct0, ct1);
      // d = m_add(-h, htil)
      float T = wred(ct0 * ct0 + ct1 * ct1);
      float U = wred(h0 * ct0 + h1 * ct1);
      float rd = 1.f / fmaxf(1.f - 2.f * U + nh2 * T, MINF);
      float cA = (1.f - 2.f * U + T) * rd, cB = (1.f - nh2) * rd;
      float d0 = -cA * h0 + cB * ct0, d1 = -cA * h1 + cB * ct1;
      // pw = m_pw(z, d)
      float zd0 = z0 * d0, zd1 = z1 * d1;
      float nd2 = wred(d0 * d0 + d1 * d1);
      float P = wred(zd0 * zd0 + zd1 * zd1);
      float Q = wred(h0 * zd0 + h1 * zd1);
      float xnd = sqrtf(fmaxf(nd2, MINF));
      float mxnp = sqrtf(fmaxf(P, MINF));
      float sp = tanhf(mxnp * artanh_c(xnd) / xnd) / mxnp;
      float pw0 = sp * zd0, pw1 = sp * zd1;
      float y2 = sp * sp * P, xy = sp * Q;
      float r3 = 1.f / fmaxf(1.f + 2.f * xy + nh2 * y2, MINF);
      float hn0 = (1.f + 2.f * xy + y2) * r3 * h0 + (1.f - nh2) * r3 * pw0;
      float hn1 = (1.f + 2.f * xy + y2) * r3 * h1 + (1.f - nh2) * r3 * pw1;
      nh2 = wred(hn0 * hn0 + hn1 * hn1);
      h0 = hn0; h1 = hn1;
      hl[row * 112 + lane] = hn0;
      if (lane < 36) hl[row * 112 + lane + 64] = hn1;
      float* fd = f + (((size_t)n * 20 + s) * 100 + b) * 200 + dir * 100;
      fd[lane] = hn0;
      if (lane < 36) fd[lane + 64] = hn1;
    }
    __syncthreads();
  }
}

// ---------------- K4a: MobiusLinear(Wp) + lorentz logits a, gamma ----------------
// grid 1334, block 256
__global__ __launch_bounds__(256) void k4a(const float* __restrict__ f, const float* __restrict__ Wp,
                                           const float* __restrict__ bp, const float* __restrict__ cl,
                                           const float* __restrict__ beta_p,
                                           float* __restrict__ a_out, float* __restrict__ g_out) {
  __shared__ float ft[24][208];
  __shared__ float wt[200][44];
  __shared__ float alx[24];
  __shared__ float nf2s[24];
  int bx = blockIdx.x; int row0 = bx * 24; int nrows = min(24, 32000 - row0);
  int t = threadIdx.x; int w = t >> 6; int lane = t & 63;
#pragma unroll
  for (int q = 0; q < 19; q++) {
    int idx = t + 256 * q;
    if (idx < 4800) {
      int r = idx / 200, c = idx % 200;
      ft[r][c] = (r < nrows) ? f[(size_t)(row0 + r) * 200 + c] : 0.f;
    }
  }
  __syncthreads();
  for (int r = w * 6; r < w * 6 + 6; r++) {
    float v0 = ft[r][lane], v1 = ft[r][lane + 64], v2 = ft[r][lane + 128];
    float v3 = (lane < 8) ? ft[r][lane + 192] : 0.f;
    float s2 = wred(v0 * v0 + v1 * v1 + v2 * v2 + v3 * v3);
    if (lane == 0) {
      nf2s[r] = s2;
      float xn = sqrtf(fmaxf(s2, MINF));
      alx[r] = artanh_c(xn) / xn;
    }
  }
  int rg = t / 25, og = t % 25; bool act = t < 200;
  float acc[3][8];
#pragma unroll
  for (int i = 0; i < 3; i++)
#pragma unroll
    for (int j = 0; j < 8; j++) acc[i][j] = 0.f;
  for (int kc = 0; kc < 5; kc++) {
    int k0 = kc * 40;
    __syncthreads();
#pragma unroll
    for (int q = 0; q < 32; q++) {
      int idx = t + 256 * q;
      if (idx < 8000) { int r = idx / 40, c = idx % 40; wt[r][c] = Wp[(size_t)r * 200 + k0 + c]; }
    }
    __syncthreads();
    if (act) {
#pragma unroll
      for (int k4 = 0; k4 < 10; k4++) {
        float4 pv[3];
#pragma unroll
        for (int i = 0; i < 3; i++) pv[i] = *(const float4*)&ft[rg * 3 + i][k0 + k4 * 4];
#pragma unroll
        for (int j = 0; j < 8; j++) {
          float4 wv = *(const float4*)&wt[og + 25 * j][k4 * 4];
#pragma unroll
          for (int i = 0; i < 3; i++)
            acc[i][j] += pv[i].x * wv.x + pv[i].y * wv.y + pv[i].z * wv.z + pv[i].w * wv.w;
        }
      }
    }
  }
  __syncthreads();
  if (act) {
#pragma unroll
    for (int i = 0; i < 3; i++)
#pragma unroll
      for (int j = 0; j < 8; j++) ft[rg * 3 + i][og + 25 * j] = acc[i][j];
  }
  __syncthreads();
  float beta = beta_p[0];
  float c200 = cl[200];
  float b_0 = bp[lane], b_1 = bp[lane + 64], b_2 = bp[lane + 128];
  float b_3 = (lane < 8) ? bp[lane + 192] : 0.f;
  float c_0 = cl[lane], c_1 = cl[lane + 64], c_2 = cl[lane + 128];
  float c_3 = (lane < 8) ? cl[lane + 192] : 0.f;
  float nbp2 = wred(b_0 * b_0 + b_1 * b_1 + b_2 * b_2 + b_3 * b_3);
  for (int r = w * 6; r < w * 6 + 6; r++) {
    if (r >= nrows) continue;
    float m0 = ft[r][lane], m1 = ft[r][lane + 64], m2 = ft[r][lane + 128];
    float m3 = (lane < 8) ? ft[r][lane + 192] : 0.f;
    float A = wred(m0 * m0 + m1 * m1 + m2 * m2 + m3 * m3);
    float B = wred(m0 * b_0 + m1 * b_1 + m2 * b_2 + m3 * b_3);
    float mxn = sqrtf(fmaxf(A, MINF));
    float gam = tanhf(mxn * alx[r]) / mxn;
    float x2 = gam * gam * A, y2 = nbp2, xy = gam * B;
    float rd = 1.f / fmaxf(1.f + 2.f * xy + x2 * y2, MINF);
    float cA = (1.f + 2.f * xy + y2) * gam * rd, cB = (1.f - x2) * rd;
    float a0 = cA * m0 + cB * b_0, a1 = cA * m1 + cB * b_1;
    float a2 = cA * m2 + cB * b_2, a3 = cA * m3 + cB * b_3;
    float r2 = wred(a0 * a0 + a1 * a1 + a2 * a2 + a3 * a3);
    float dc = wred(a0 * c_0 + a1 * c_1 + a2 * c_2 + a3 * c_3);
    float pm = (-2.f * dc + (1.f + r2) * c200) / (1.f - r2 + EPSF);
    pm = fminf(fmaxf(pm, 1.f + EPSF), 1e16f);
    float av = -beta * arcosh_(pm) - 1.f;
    float nf2 = nf2s[r];
    float invg = 1.f - 4.f * nf2 / ((1.f + nf2) * (1.f + nf2));
    invg = fminf(fmaxf(invg, EPSF), 1.f - EPSF);
    float gv = fminf(fmaxf(1.f / sqrtf(invg), 1.f + EPSF), 1e16f);
    if (lane == 0) { a_out[row0 + r] = av; g_out[row0 + r] = gv; }
  }
}

// ---------------- K4b: per-sample softmax weights ----------------
// grid 16, block 256
__global__ __launch_bounds__(256) void k4b(const float* __restrict__ a_in,
                                           const float* __restrict__ g_in,
                                           float* __restrict__ wgt) {
  __shared__ float rl[2000];
  __shared__ float sred[4];
  __shared__ float rsinv[100];
  int n = blockIdx.x; int t = threadIdx.x;
  int w = t >> 6, lane = t & 63;
  const float* ap = a_in + n * 2000;
  const float* gp = g_in + n * 2000;
  float av[8]; float am = -1e30f;
#pragma unroll
  for (int q = 0; q < 8; q++) {
    int i = t + 256 * q;
    av[q] = (i < 2000) ? ap[i] : -1e30f;
    am = fmaxf(am, av[q]);
  }
  am = wredmax(am);
  if (lane == 0) sred[w] = am;
  __syncthreads();
  float amax = fmaxf(fmaxf(sred[0], sred[1]), fmaxf(sred[2], sred[3]));
#pragma unroll
  for (int q = 0; q < 8; q++) {
    int i = t + 256 * q;
    if (i < 2000) rl[i] = expf(av[q] - amax) * gp[i];
  }
  __syncthreads();
  if (t < 100) {
    float ssum = 0.f;
#pragma unroll
    for (int s = 0; s < 20; s++) ssum += rl[s * 100 + t];
    rsinv[t] = 1.f / ssum;
  }
  __syncthreads();
#pragma unroll
  for (int q = 0; q < 8; q++) {
    int i = t + 256 * q;
    if (i < 2000) wgt[n * 2000 + i] = rl[i] * rsinv[i % 100];
  }
}

// ---------------- K4c: klein aggregation + final GEMM W2 ----------------
// grid 320 (n,s), block 256
__global__ __launch_bounds__(256) void k4c(const float* __restrict__ f, const float* __restrict__ wgt,
                                           const float* __restrict__ W2, const float* __restrict__ b2,
                                           float* __restrict__ out) {
  __shared__ float cw[100];
  __shared__ float ol[200];
  __shared__ float sred[4];
  int bx = blockIdx.x; int n = bx / 20, s = bx % 20;
  int t = threadIdx.x; int w = t >> 6; int lane = t & 63;
  const float* fb = f + ((size_t)n * 20 + s) * 100 * 200;
  for (int bi = w * 25; bi < w * 25 + 25; bi++) {
    const float* fr = fb + bi * 200;
    float v0 = fr[lane], v1 = fr[lane + 64], v2 = fr[lane + 128];
    float v3 = (lane < 8) ? fr[lane + 192] : 0.f;
    float s2 = wred(v0 * v0 + v1 * v1 + v2 * v2 + v3 * v3);
    if (lane == 0) cw[bi] = wgt[n * 2000 + s * 100 + bi] * 2.f / (1.f + s2);
  }
  __syncthreads();
  float o = 0.f;
  if (t < 200) {
    for (int bi = 0; bi < 100; bi++) o += cw[bi] * fb[bi * 200 + t];
  }
  float ps = (t < 200) ? o * o : 0.f;
  ps = wred(ps);
  if (lane == 0) sred[w] = ps;
  __syncthreads();
  float no2 = sred[0] + sred[1] + sred[2] + sred[3];
  float denom = 1.f + sqrtf(1.f + no2);
  if (t < 200) ol[t] = o / denom;
  __syncthreads();
  const float4* ol4 = (const float4*)ol;
#pragma unroll
  for (int jj = 0; jj < 3; jj++) {
    int j = t + 256 * jj;
    const float4* wrow = (const float4*)(W2 + (size_t)j * 200);
    float a0 = 0, a1 = 0, a2 = 0, a3 = 0;
    for (int k4 = 0; k4 < 50; k4++) {
      float4 wv = wrow[k4]; float4 ov = ol4[k4];
      a0 += wv.x * ov.x; a1 += wv.y * ov.y; a2 += wv.z * ov.z; a3 += wv.w * ov.w;
    }
    out[((size_t)n * 20 + s) * 768 + j] = a0 + a1 + a2 + a3 + b2[j];
  }
}

extern "C" void kernel_launch(void* const* d_in, const int* in_sizes, int n_in,
                              void* d_out, int out_size, void* d_ws, size_t ws_size,
                              hipStream_t stream) {
  const float* x_     = (const float*)d_in[0];
  const float* W1     = (const float*)d_in[1];
  const float* b1     = (const float*)d_in[2];
  const float* W2     = (const float*)d_in[3];
  const float* b2     = (const float*)d_in[4];
  const float* Wih_f  = (const float*)d_in[5];
  const float* Whh_f  = (const float*)d_in[6];
  const float* bias_f = (const float*)d_in[7];
  const float* Wih_b  = (const float*)d_in[8];
  const float* Whh_b  = (const float*)d_in[9];
  const float* bias_b = (const float*)d_in[10];
  const float* centroid = (const float*)d_in[11];
  const float* Wp     = (const float*)d_in[12];
  const float* bp     = (const float*)d_in[13];
  const float* beta   = (const float*)d_in[14];
  float* out = (float*)d_out;
  float* ws = (float*)d_ws;
  float* p   = ws + OFF_P;
  float* ux  = ws + OFF_UX;
  float* wt4 = ws + OFF_WT4;
  float* f   = ws + OFF_F;
  float* wi4 = ws + OFF_WI4;
  float* w1p = ws + OFF_W1P;
  float* cl  = ws + OFF_CL;
  float* aa  = ws + OFF_A;
  float* gg  = ws + OFF_G;
  float* wg  = ws + OFF_WGT;

  (void)hipFuncSetAttribute(reinterpret_cast<const void*>(k3),
                            hipFuncAttributeMaxDynamicSharedMemorySize, K3_LDS_BYTES);
  (void)hipFuncSetAttribute(reinterpret_cast<const void*>(k2),
                            hipFuncAttributeMaxDynamicSharedMemorySize, K2_LDS_BYTES);

  k0_pack<<<769, 256, 0, stream>>>(Whh_f, Whh_b, Wih_f, Wih_b, W1, wt4, wi4, w1p);
  k0_cl<<<1, 256, 0, stream>>>(centroid, cl);
  k1<<<500, 256, 0, stream>>>(x_, w1p, b1, p);
  k2<<<3000, 256, K2_LDS_BYTES, stream>>>(p, wi4, ux);
  k3<<<256, 1024, K3_LDS_BYTES, stream>>>(ux, wt4, bias_f, bias_b, f);
  k4a<<<1334, 256, 0, stream>>>(f, Wp, bp, cl, beta, aa, gg);
  k4b<<<16, 256, 0, stream>>>(aa, gg, wg);
  k4c<<<320, 256, 0, stream>>>(f, wg, W2, b2, out);
}

// Round 4
// 998.574 us; speedup vs baseline: 3.1583x; 1.1723x over previous
//
#include <hip/hip_runtime.h>
#include <hip/hip_bf16.h>

#define MINF 1e-15f
#define EPSF 1e-6f

// ---------- workspace layout (floats) ----------
#define OFF_P    0u            // 16*2000*100      = 3,200,000
#define OFF_UX   3200000u      // 2*3*32000*100    = 19,200,000
#define OFF_WT4  22400000u     // 2*3*25*100*4     = 60,000
#define OFF_F    22460000u     // 16*20*100*200    = 6,400,000
#define OFF_CL   28860000u     // 201 (pad 256)
#define OFF_A    28860256u     // 32000
#define OFF_G    28892256u     // 32000
#define OFF_WGT  28924256u     // 32000
// Region reuse (all stream-ordered, re-packed every call):
//   wi4/w1p live in the f region until k3 overwrites f.
//   mx (32000x200 raw Wp-GEMM output) reuses the ux region (dead after k3).
//   wp4 (40,000) reuses the aa/gg region (dead until k4ae writes aa/gg).
#define OFF_WI4  OFF_F
#define OFF_W1P  (OFF_F + 60000u)
#define OFF_MX   OFF_UX
#define OFF_WP4  OFF_A

#define K3_LDS_BYTES 149120    // (30000 + 13*3*112 + 13*112 + 13*112) * 4
#define K2_LDS_BYTES ((3200 + 64*26)*16 + 64*4)   // W 51200 + p 26624 + alx 256 = 78080
#define K4G_LDS_BYTES ((3200 + 64*26)*16)         // W 51200 + f 26624 = 77824

__device__ __forceinline__ float wred(float v) {
#pragma unroll
  for (int m = 32; m > 0; m >>= 1) v += __shfl_xor(v, m, 64);
  return v;
}
__device__ __forceinline__ float wredmax(float v) {
#pragma unroll
  for (int m = 32; m > 0; m >>= 1) v = fmaxf(v, __shfl_xor(v, m, 64));
  return v;
}
__device__ __forceinline__ float artanh_c(float x) {
  x = fminf(x, 1.f - 1e-7f);
  return 0.5f * (log1pf(x) - log1pf(-x));
}
__device__ __forceinline__ float arcosh_(float x) {
  return logf(x) + log1pf(sqrtf(fmaxf(x * x - 1.f + EPSF, 0.f)) / x);
}
__device__ __forceinline__ float sigm(float x) { return 1.f / (1.f + expf(-x)); }

// ---------------- K0a: pack weights into float4-friendly layouts ----------------
// Whh -> wt4 [dir][g][k4][j][4]          (k3 mv100)
// Wih -> wi4 [combo][k4][c][4]           (k2 GEMM)
// W1  -> w1p [k4][c][4], k4 in [0,192)   (k1 GEMM)
// Wp  -> wp4 [ch][k4(50)][c(100)][4]     (k4ag GEMM; ch = column half)
__global__ void k0_pack(const float* __restrict__ whh_f, const float* __restrict__ whh_b,
                        const float* __restrict__ wih_f, const float* __restrict__ wih_b,
                        const float* __restrict__ W1, const float* __restrict__ Wp,
                        float* __restrict__ wt4, float* __restrict__ wi4,
                        float* __restrict__ w1p, float* __restrict__ wp4) {
  int idx = blockIdx.x * 256 + threadIdx.x;
  if (idx < 60000) {
    int kk = idx & 3; int t = idx >> 2;
    int j = t % 100; t /= 100;
    int k4 = t % 25; t /= 25;
    int g = t % 3; int dir = t / 3;
    const float* src = dir ? whh_b : whh_f;
    wt4[idx] = src[g * 10000 + j * 100 + k4 * 4 + kk];
  } else if (idx < 120000) {
    int i2 = idx - 60000;
    int kk = i2 & 3; int t = i2 >> 2;
    int c = t % 100; t /= 100;
    int k4 = t % 25; t /= 25;
    int g = t % 3; int dir = t / 3;
    const float* src = dir ? wih_b : wih_f;
    wi4[i2] = src[g * 10000 + c * 100 + k4 * 4 + kk];
  } else if (idx < 196800) {
    int i2 = idx - 120000;
    int kk = i2 & 3; int t = i2 >> 2;
    int c = t % 100; int k4 = t / 100;
    w1p[i2] = W1[c * 768 + k4 * 4 + kk];
  } else if (idx < 236800) {
    int i3 = idx - 196800;
    int kk = i3 & 3; int t = i3 >> 2;
    int c = t % 100; int t2 = t / 100;       // t2 = ch*50 + k4
    int k4 = t2 % 50; int ch = t2 / 50;
    wp4[i3] = Wp[(size_t)(ch * 100 + c) * 200 + k4 * 4 + kk];
  }
}

// ---------------- K0b: lorentz_activation(centroid) -> cl[201] ----------------
__global__ void k0_cl(const float* __restrict__ centroid, float* __restrict__ cl) {
  __shared__ float sred[4];
  int t = threadIdx.x;
  float v = (t < 200) ? centroid[t] : 0.f;
  float ps = wred(v * v);
  if ((t & 63) == 0) sred[t >> 6] = ps;
  __syncthreads();
  float r = sqrtf(sred[0] + sred[1] + sred[2] + sred[3]);
  if (t < 200) cl[t] = v / r * sinhf(r);
  if (t == 0) cl[200] = coshf(r);
}

// ---------------- K1: klein(x_) @ W1^T + b1, poincare project -> p ----------------
// Register-tiled GEMM: 64 rows x 128 cols (100 live) per block, K=768 in 12 chunks.
__global__ __launch_bounds__(256, 2) void k1(const float* __restrict__ x_,
                                             const float* __restrict__ w1p,
                                             const float* __restrict__ b1,
                                             float* __restrict__ p) {
  __shared__ float4 wl[16 * 128];
  __shared__ float4 xl[64 * 16];
  __shared__ float ns[64];
  __shared__ float sscale[64];
  int t = threadIdx.x;
  int row0 = blockIdx.x * 64;
  int cg = t & 31, rg = t >> 5;
  const float4* wsrc = (const float4*)w1p;
  float nacc[4] = {0, 0, 0, 0};
  float acc[8][4] = {};
  for (int kc = 0; kc < 12; kc++) {
    int k0f4 = kc * 16;
    __syncthreads();
#pragma unroll
    for (int q = 0; q < 4; q++) {
      int idx = t + 256 * q;
      int r = idx >> 4, c4 = idx & 15;
      float4 v = *(const float4*)(x_ + (size_t)(row0 + r) * 768 + (size_t)(k0f4 + c4) * 4);
      xl[idx] = v;
      nacc[q] += v.x * v.x + v.y * v.y + v.z * v.z + v.w * v.w;
    }
#pragma unroll
    for (int q = 0; q < 8; q++) {
      int idx = t + 256 * q;
      int k4 = idx >> 7, c = idx & 127;
      float4 v = {0, 0, 0, 0};
      if (c < 100) v = wsrc[(size_t)(k0f4 + k4) * 100 + c];
      wl[idx] = v;
    }
    __syncthreads();
#pragma unroll 4
    for (int k4 = 0; k4 < 16; k4++) {
      float4 wv[4];
#pragma unroll
      for (int j = 0; j < 4; j++) wv[j] = wl[k4 * 128 + cg + 32 * j];
#pragma unroll
      for (int i = 0; i < 8; i++) {
        float4 pv = xl[(rg * 8 + i) * 16 + k4];
#pragma unroll
        for (int j = 0; j < 4; j++)
          acc[i][j] += pv.x * wv[j].x + pv.y * wv[j].y + pv.z * wv[j].z + pv.w * wv[j].w;
      }
    }
  }
  __syncthreads();
#pragma unroll
  for (int q = 0; q < 4; q++) {
    float v = nacc[q];
#pragma unroll
    for (int m = 8; m > 0; m >>= 1) v += __shfl_xor(v, m, 64);
    if ((t & 15) == 0) ns[(t >> 4) + 16 * q] = v;
  }
  __syncthreads();
  if (t < 64) {
    float rr = sqrtf(fmaxf(ns[t], MINF));
    sscale[t] = tanhf(rr) / rr;
  }
  __syncthreads();
  float bcol[4];
#pragma unroll
  for (int j = 0; j < 4; j++) {
    int col = cg + 32 * j;
    bcol[j] = (col < 100) ? b1[col] : 0.f;
  }
#pragma unroll
  for (int i = 0; i < 8; i++) {
    int r = rg * 8 + i;
    float s = sscale[r];
    float hv[4]; float ss = 0.f;
#pragma unroll
    for (int j = 0; j < 4; j++) {
      int col = cg + 32 * j;
      hv[j] = (col < 100) ? (s * acc[i][j] + bcol[j]) : 0.f;
      ss += hv[j] * hv[j];
    }
#pragma unroll
    for (int m = 16; m > 0; m >>= 1) ss += __shfl_xor(ss, m, 64);
    float inv = 1.f / sqrtf(1.f + ss);
    float* prow = p + (size_t)(row0 + r) * 100;
#pragma unroll
    for (int j = 0; j < 4; j++) {
      int col = cg + 32 * j;
      if (col < 100) prow[col] = hv[j] * inv;
    }
  }
}

// ---------------- K2: ux[combo][row] = m_matvec(Wih_combo, p[row]) ----------------
__global__ __launch_bounds__(256, 2) void k2(const float* __restrict__ p,
                                             const float* __restrict__ wi4,
                                             float* __restrict__ ux) {
  extern __shared__ float4 l4[];
  float4* wl = l4;
  float4* pl = l4 + 3200;
  float* alx = (float*)(l4 + 3200 + 64 * 26);
  int t = threadIdx.x;
  int bx = blockIdx.x;
  int combo = bx / 500, tile = bx % 500;
  int row0 = tile * 64;
  int cg = t & 31, rg = t >> 5;
  const float4* wsrc = (const float4*)wi4 + (size_t)combo * 2500;
#pragma unroll
  for (int q = 0; q < 13; q++) {
    int idx = t + 256 * q;
    if (idx < 3200) {
      int k4 = idx >> 7, c = idx & 127;
      float4 v = {0, 0, 0, 0};
      if (c < 100) v = wsrc[k4 * 100 + c];
      wl[idx] = v;
    }
  }
  const float4* psrc = (const float4*)(p + (size_t)row0 * 100);
#pragma unroll
  for (int q = 0; q < 7; q++) {
    int idx = t + 256 * q;
    if (idx < 1600) {
      int r = idx / 25, c4 = idx % 25;
      pl[r * 26 + c4] = psrc[idx];
    }
  }
  __syncthreads();
  {
    int w = t >> 6, lane = t & 63;
    const float* pf = (const float*)pl;
    for (int r = w * 16; r < w * 16 + 16; r++) {
      float v0 = pf[r * 104 + lane];
      float v1 = (lane < 36) ? pf[r * 104 + 64 + lane] : 0.f;
      float s2 = wred(v0 * v0 + v1 * v1);
      if (lane == 0) {
        float xn = sqrtf(fmaxf(s2, MINF));
        alx[r] = artanh_c(xn) / xn;
      }
    }
  }
  __syncthreads();
  float acc[8][4] = {};
#pragma unroll 5
  for (int k4 = 0; k4 < 25; k4++) {
    float4 wv[4];
#pragma unroll
    for (int j = 0; j < 4; j++) wv[j] = wl[k4 * 128 + cg + 32 * j];
#pragma unroll
    for (int i = 0; i < 8; i++) {
      float4 pv = pl[(rg * 8 + i) * 26 + k4];
#pragma unroll
      for (int j = 0; j < 4; j++)
        acc[i][j] += pv.x * wv[j].x + pv.y * wv[j].y + pv.z * wv[j].z + pv.w * wv[j].w;
    }
  }
#pragma unroll
  for (int i = 0; i < 8; i++) {
    int r = rg * 8 + i;
    float ss = acc[i][0] * acc[i][0] + acc[i][1] * acc[i][1] +
               acc[i][2] * acc[i][2] + acc[i][3] * acc[i][3];
#pragma unroll
    for (int m = 16; m > 0; m >>= 1) ss += __shfl_xor(ss, m, 64);
    float mxn = sqrtf(fmaxf(ss, MINF));
    float sc = tanhf(mxn * alx[r]) / mxn;
    float* dst = ux + ((size_t)combo * 32000 + row0 + r) * 100;
#pragma unroll
    for (int j = 0; j < 4; j++) {
      int col = cg + 32 * j;
      if (col < 100) dst[col] = sc * acc[i][j];
    }
  }
}

// ---------------- K3: sequential Mobius GRU ----------------
__device__ __forceinline__ void mv100(const float* __restrict__ Wg, const float* __restrict__ hrow,
                                      float* __restrict__ out, int lane) {
  const float4* W4 = (const float4*)Wg;
  const float4* h4 = (const float4*)hrow;
  float4 a0 = {0, 0, 0, 0}, a1 = {0, 0, 0, 0};
#pragma unroll 5
  for (int k4 = 0; k4 < 25; k4++) {
    float4 hv = h4[k4];
    float4 w0 = W4[k4 * 100 + lane];
    a0.x += w0.x * hv.x; a0.y += w0.y * hv.y; a0.z += w0.z * hv.z; a0.w += w0.w * hv.w;
    if (lane < 36) {
      float4 w1 = W4[k4 * 100 + lane + 64];
      a1.x += w1.x * hv.x; a1.y += w1.y * hv.y; a1.z += w1.z * hv.z; a1.w += w1.w * hv.w;
    }
  }
  out[lane] = a0.x + a0.y + a0.z + a0.w;
  if (lane < 36) out[64 + lane] = a1.x + a1.y + a1.z + a1.w;
}

// Fused z+r matvec: shares the h broadcast loads + loop/addr overhead; halves
// the M1 task count so one balanced round over 16 waves replaces two.
__device__ __forceinline__ void mv100x2(const float* __restrict__ Wz, const float* __restrict__ Wr,
                                        const float* __restrict__ hrow,
                                        float* __restrict__ outz, float* __restrict__ outr,
                                        int lane) {
  const float4* Wz4 = (const float4*)Wz;
  const float4* Wr4 = (const float4*)Wr;
  const float4* h4 = (const float4*)hrow;
  float4 az0 = {0, 0, 0, 0}, az1 = {0, 0, 0, 0};
  float4 ar0 = {0, 0, 0, 0}, ar1 = {0, 0, 0, 0};
#pragma unroll 5
  for (int k4 = 0; k4 < 25; k4++) {
    float4 hv = h4[k4];
    float4 wz0 = Wz4[k4 * 100 + lane];
    float4 wr0 = Wr4[k4 * 100 + lane];
    az0.x += wz0.x * hv.x; az0.y += wz0.y * hv.y; az0.z += wz0.z * hv.z; az0.w += wz0.w * hv.w;
    ar0.x += wr0.x * hv.x; ar0.y += wr0.y * hv.y; ar0.z += wr0.z * hv.z; ar0.w += wr0.w * hv.w;
    if (lane < 36) {
      float4 wz1 = Wz4[k4 * 100 + lane + 64];
      float4 wr1 = Wr4[k4 * 100 + lane + 64];
      az1.x += wz1.x * hv.x; az1.y += wz1.y * hv.y; az1.z += wz1.z * hv.z; az1.w += wz1.w * hv.w;
      ar1.x += wr1.x * hv.x; ar1.y += wr1.y * hv.y; ar1.z += wr1.z * hv.z; ar1.w += wr1.w * hv.w;
    }
  }
  outz[lane] = az0.x + az0.y + az0.z + az0.w;
  outr[lane] = ar0.x + ar0.y + ar0.z + ar0.w;
  if (lane < 36) {
    outz[64 + lane] = az1.x + az1.y + az1.z + az1.w;
    outr[64 + lane] = ar1.x + ar1.y + ar1.z + ar1.w;
  }
}

__device__ __forceinline__ void onetrans(const float* __restrict__ mv, float ux0, float ux1,
                                         float alphax, float b_0, float b_1, float nb2, int lane,
                                         float& c0, float& c1) {
  float m0 = mv[lane];
  float m1 = (lane < 36) ? mv[64 + lane] : 0.f;
  float A = wred(m0 * m0 + m1 * m1);
  float B = wred(m0 * ux0 + m1 * ux1);
  float C = wred(ux0 * ux0 + ux1 * ux1);
  float mxn = sqrtf(fmaxf(A, MINF));
  float gam = tanhf(mxn * alphax) / mxn;
  float x2 = gam * gam * A, y2 = C, xy = gam * B;
  float rd = 1.f / fmaxf(1.f + 2.f * xy + x2 * y2, MINF);
  float cA = (1.f + 2.f * xy + y2) * gam * rd, cB = (1.f - x2) * rd;
  float a0 = cA * m0 + cB * ux0, a1 = cA * m1 + cB * ux1;
  float D = wred(a0 * a0 + a1 * a1);
  float E = wred(a0 * b_0 + a1 * b_1);
  float r2 = 1.f / fmaxf(1.f + 2.f * E + D * nb2, MINF);
  float t1 = (1.f + 2.f * E + nb2) * r2, t2 = (1.f - D) * r2;
  c0 = t1 * a0 + t2 * b_0;
  c1 = t1 * a1 + t2 * b_1;
}

// grid 256 (32 groups x 8 row-chunks), block 1024, dyn LDS 149120 B
__global__ __launch_bounds__(1024, 4) void k3(const float* __restrict__ ux,
                                              const float* __restrict__ wt4,
                                              const float* __restrict__ bias_f,
                                              const float* __restrict__ bias_b,
                                              float* __restrict__ f) {
  extern __shared__ float lds[];
  float* Wlds = lds;                 // 30000
  float* mvl = lds + 30000;          // 13*3*112
  float* hl = mvl + 13 * 3 * 112;    // 13*112
  float* rhl = hl + 13 * 112;        // 13*112
  int t = threadIdx.x; int w = t >> 6; int lane = t & 63;
  int bx = blockIdx.x;
  int grp = bx >> 3; int blki = bx & 7;
  int n = grp >> 1; int dir = grp & 1;
  int b0 = blki * 13; int nrows = min(13, 100 - b0);
  const float* bias = dir ? bias_b : bias_f;
  const float* wsrc = wt4 + dir * 30000;
#pragma unroll
  for (int q = 0; q < 30; q++) { int idx = t + 1024 * q; if (idx < 30000) Wlds[idx] = wsrc[idx]; }
#pragma unroll
  for (int q = 0; q < 2; q++) { int idx = t + 1024 * q; if (idx < 13 * 112) hl[idx] = 0.f; }
  __syncthreads();

  int row = w; bool erow = (w < nrows);
  int b = b0 + row;
  float nh2 = 0.f, h0 = 0.f, h1 = 0.f;
  float bz0 = 0, bz1 = 0, br0 = 0, br1 = 0, bh0 = 0, bh1 = 0, nbz2 = 0, nbr2 = 0, nbh2 = 0;
  if (erow) {
    br0 = bias[lane];        if (lane < 36) br1 = bias[64 + lane];
    bh0 = bias[100 + lane];  if (lane < 36) bh1 = bias[164 + lane];
    bz0 = bias[200 + lane];  if (lane < 36) bz1 = bias[264 + lane];
    nbr2 = wred(br0 * br0 + br1 * br1);
    nbh2 = wred(bh0 * bh0 + bh1 * bh1);
    nbz2 = wred(bz0 * bz0 + bz1 * bz1);
  }
  for (int s = 0; s < 20; s++) {
    // M1: fused z(g=2)+r(g=0) matvecs, one row per wave (13 tasks / 16 waves)
    for (int mrow = w; mrow < nrows; mrow += 16) {
      mv100x2(Wlds + 2 * 10000, Wlds + 0 * 10000, hl + mrow * 112,
              mvl + (mrow * 3 + 2) * 112, mvl + (mrow * 3 + 0) * 112, lane);
    }
    __syncthreads();
    float z0 = 0, z1 = 0, uxh0 = 0, uxh1 = 0, nrh2 = 0;
    if (erow) {
      int l = dir ? (1999 - (s * 100 + b)) : (s * 100 + b);
      size_t rowg = (size_t)n * 2000 + l;
      const float* uxz = ux + ((size_t)(dir * 3 + 2) * 32000 + rowg) * 100;
      const float* uxr = ux + ((size_t)(dir * 3 + 0) * 32000 + rowg) * 100;
      const float* uxh = ux + ((size_t)(dir * 3 + 1) * 32000 + rowg) * 100;
      float uz0 = uxz[lane], uz1 = (lane < 36) ? uxz[lane + 64] : 0.f;
      float ur0 = uxr[lane], ur1 = (lane < 36) ? uxr[lane + 64] : 0.f;
      uxh0 = uxh[lane]; uxh1 = (lane < 36) ? uxh[lane + 64] : 0.f;
      float xnh = sqrtf(fmaxf(nh2, MINF));
      float alphah = artanh_c(xnh) / xnh;
      float cz0, cz1, cr0, cr1;
      onetrans(mvl + (row * 3 + 2) * 112, uz0, uz1, alphah, bz0, bz1, nbz2, lane, cz0, cz1);
      onetrans(mvl + (row * 3 + 0) * 112, ur0, ur1, alphah, br0, br1, nbr2, lane, cr0, cr1);
      float Fz = wred(cz0 * cz0 + cz1 * cz1);
      float cnz = sqrtf(fmaxf(Fz, MINF)); float lgz = artanh_c(cnz) / cnz;
      z0 = sigm(lgz * cz0); z1 = sigm(lgz * cz1);
      float Fr = wred(cr0 * cr0 + cr1 * cr1);
      float cnr = sqrtf(fmaxf(Fr, MINF)); float lgr = artanh_c(cnr) / cnr;
      float r0 = sigm(lgr * cr0), r1 = sigm(lgr * cr1);
      float mx0 = r0 * h0, mx1 = r1 * h1;
      float G = wred(mx0 * mx0 + mx1 * mx1);
      float mxnr = sqrtf(fmaxf(G, MINF));
      float srh = tanhf(mxnr * alphah) / mxnr;
      rhl[row * 112 + lane] = srh * mx0;
      if (lane < 36) rhl[row * 112 + lane + 64] = srh * mx1;
      nrh2 = srh * srh * G;
      mv100(Wlds + 1 * 10000, rhl + row * 112, mvl + (row * 3 + 1) * 112, lane);
      float xnrh = sqrtf(fmaxf(nrh2, MINF));
      float alpharh = artanh_c(xnrh) / xnrh;
      float ct0, ct1;
      onetrans(mvl + (row * 3 + 1) * 112, uxh0, uxh1, alpharh, bh0, bh1, nbh2, lane, ct0, ct1);
      float T = wred(ct0 * ct0 + ct1 * ct1);
      float U = wred(h0 * ct0 + h1 * ct1);
      float rd = 1.f / fmaxf(1.f - 2.f * U + nh2 * T, MINF);
      float cA = (1.f - 2.f * U + T) * rd, cB = (1.f - nh2) * rd;
      float d0 = -cA * h0 + cB * ct0, d1 = -cA * h1 + cB * ct1;
      float zd0 = z0 * d0, zd1 = z1 * d1;
      float nd2 = wred(d0 * d0 + d1 * d1);
      float P = wred(zd0 * zd0 + zd1 * zd1);
      float Q = wred(h0 * zd0 + h1 * zd1);
      float xnd = sqrtf(fmaxf(nd2, MINF));
      float mxnp = sqrtf(fmaxf(P, MINF));
      float sp = tanhf(mxnp * artanh_c(xnd) / xnd) / mxnp;
      float pw0 = sp * zd0, pw1 = sp * zd1;
      float y2 = sp * sp * P, xy = sp * Q;
      float r3 = 1.f / fmaxf(1.f + 2.f * xy + nh2 * y2, MINF);
      float hn0 = (1.f + 2.f * xy + y2) * r3 * h0 + (1.f - nh2) * r3 * pw0;
      float hn1 = (1.f + 2.f * xy + y2) * r3 * h1 + (1.f - nh2) * r3 * pw1;
      nh2 = wred(hn0 * hn0 + hn1 * hn1);
      h0 = hn0; h1 = hn1;
      hl[row * 112 + lane] = hn0;
      if (lane < 36) hl[row * 112 + lane + 64] = hn1;
      float* fd = f + (((size_t)n * 20 + s) * 100 + b) * 200 + dir * 100;
      fd[lane] = hn0;
      if (lane < 36) fd[lane + 64] = hn1;
    }
    __syncthreads();
  }
}

// ---------------- K4ag: mx = f @ Wp^T (raw), register-tiled ----------------
// grid 1000 (500 row-tiles x 2 col-halves), block 256, dyn LDS 77824 B.
__global__ __launch_bounds__(256, 2) void k4ag(const float* __restrict__ f,
                                               const float* __restrict__ wp4,
                                               float* __restrict__ mx) {
  extern __shared__ float4 g4[];
  float4* wl = g4;                 // 3200: [25 k4][128 c]
  float4* pl = g4 + 3200;          // 64*26: [64 r][25 k4 + pad]
  int t = threadIdx.x;
  int bx = blockIdx.x;
  int ch = bx & 1, tile = bx >> 1;
  int row0 = tile * 64;
  int cg = t & 31, rg = t >> 5;
  const float4* wsrc = (const float4*)wp4 + (size_t)ch * 5000;
  const float4* psrc = (const float4*)(f + (size_t)row0 * 200);
  float acc[8][4] = {};
  for (int kc = 0; kc < 2; kc++) {
    __syncthreads();
#pragma unroll
    for (int q = 0; q < 13; q++) {
      int idx = t + 256 * q;
      if (idx < 3200) {
        int k4 = idx >> 7, c = idx & 127;
        float4 v = {0, 0, 0, 0};
        if (c < 100) v = wsrc[(kc * 25 + k4) * 100 + c];
        wl[idx] = v;
      }
    }
#pragma unroll
    for (int q = 0; q < 7; q++) {
      int idx = t + 256 * q;
      if (idx < 1600) {
        int r = idx / 25, k4 = idx % 25;
        pl[r * 26 + k4] = psrc[r * 50 + kc * 25 + k4];
      }
    }
    __syncthreads();
#pragma unroll 5
    for (int k4 = 0; k4 < 25; k4++) {
      float4 wv[4];
#pragma unroll
      for (int j = 0; j < 4; j++) wv[j] = wl[k4 * 128 + cg + 32 * j];
#pragma unroll
      for (int i = 0; i < 8; i++) {
        float4 pv = pl[(rg * 8 + i) * 26 + k4];
#pragma unroll
        for (int j = 0; j < 4; j++)
          acc[i][j] += pv.x * wv[j].x + pv.y * wv[j].y + pv.z * wv[j].z + pv.w * wv[j].w;
      }
    }
  }
#pragma unroll
  for (int i = 0; i < 8; i++) {
    float* dst = mx + (size_t)(row0 + rg * 8 + i) * 200 + ch * 100;
#pragma unroll
    for (int j = 0; j < 4; j++) {
      int col = cg + 32 * j;
      if (col < 100) dst[col] = acc[i][j];
    }
  }
}

// ---------------- K4ae: Mobius m_add(bp) + lorentz logits a, gamma ----------------
// grid 500, block 256 (4 waves x 16 rows)
__global__ __launch_bounds__(256) void k4ae(const float* __restrict__ f,
                                            const float* __restrict__ mx,
                                            const float* __restrict__ bp,
                                            const float* __restrict__ cl,
                                            const float* __restrict__ beta_p,
                                            float* __restrict__ a_out, float* __restrict__ g_out) {
  int t = threadIdx.x; int w = t >> 6; int lane = t & 63;
  int row0 = blockIdx.x * 64;
  float beta = beta_p[0];
  float c200 = cl[200];
  float b_0 = bp[lane], b_1 = bp[lane + 64], b_2 = bp[lane + 128];
  float b_3 = (lane < 8) ? bp[lane + 192] : 0.f;
  float c_0 = cl[lane], c_1 = cl[lane + 64], c_2 = cl[lane + 128];
  float c_3 = (lane < 8) ? cl[lane + 192] : 0.f;
  float nbp2 = wred(b_0 * b_0 + b_1 * b_1 + b_2 * b_2 + b_3 * b_3);
  for (int r = w * 16; r < w * 16 + 16; r++) {
    const float* fr = f + (size_t)(row0 + r) * 200;
    const float* mr = mx + (size_t)(row0 + r) * 200;
    float f0 = fr[lane], f1 = fr[lane + 64], f2 = fr[lane + 128];
    float f3 = (lane < 8) ? fr[lane + 192] : 0.f;
    float nf2 = wred(f0 * f0 + f1 * f1 + f2 * f2 + f3 * f3);
    float xn = sqrtf(fmaxf(nf2, MINF));
    float alx = artanh_c(xn) / xn;
    float m0 = mr[lane], m1 = mr[lane + 64], m2 = mr[lane + 128];
    float m3 = (lane < 8) ? mr[lane + 192] : 0.f;
    float A = wred(m0 * m0 + m1 * m1 + m2 * m2 + m3 * m3);
    float B = wred(m0 * b_0 + m1 * b_1 + m2 * b_2 + m3 * b_3);
    float mxn = sqrtf(fmaxf(A, MINF));
    float gam = tanhf(mxn * alx) / mxn;
    float x2 = gam * gam * A, y2 = nbp2, xy = gam * B;
    float rd = 1.f / fmaxf(1.f + 2.f * xy + x2 * y2, MINF);
    float cA = (1.f + 2.f * xy + y2) * gam * rd, cB = (1.f - x2) * rd;
    float a0 = cA * m0 + cB * b_0, a1 = cA * m1 + cB * b_1;
    float a2 = cA * m2 + cB * b_2, a3 = cA * m3 + cB * b_3;
    float r2 = wred(a0 * a0 + a1 * a1 + a2 * a2 + a3 * a3);
    float dc = wred(a0 * c_0 + a1 * c_1 + a2 * c_2 + a3 * c_3);
    float pm = (-2.f * dc + (1.f + r2) * c200) / (1.f - r2 + EPSF);
    pm = fminf(fmaxf(pm, 1.f + EPSF), 1e16f);
    float av = -beta * arcosh_(pm) - 1.f;
    float invg = 1.f - 4.f * nf2 / ((1.f + nf2) * (1.f + nf2));
    invg = fminf(fmaxf(invg, EPSF), 1.f - EPSF);
    float gv = fminf(fmaxf(1.f / sqrtf(invg), 1.f + EPSF), 1e16f);
    if (lane == 0) { a_out[row0 + r] = av; g_out[row0 + r] = gv; }
  }
}

// ---------------- K4b: per-sample softmax weights ----------------
__global__ __launch_bounds__(256) void k4b(const float* __restrict__ a_in,
                                           const float* __restrict__ g_in,
                                           float* __restrict__ wgt) {
  __shared__ float rl[2000];
  __shared__ float sred[4];
  __shared__ float rsinv[100];
  int n = blockIdx.x; int t = threadIdx.x;
  int w = t >> 6, lane = t & 63;
  const float* ap = a_in + n * 2000;
  const float* gp = g_in + n * 2000;
  float av[8]; float am = -1e30f;
#pragma unroll
  for (int q = 0; q < 8; q++) {
    int i = t + 256 * q;
    av[q] = (i < 2000) ? ap[i] : -1e30f;
    am = fmaxf(am, av[q]);
  }
  am = wredmax(am);
  if (lane == 0) sred[w] = am;
  __syncthreads();
  float amax = fmaxf(fmaxf(sred[0], sred[1]), fmaxf(sred[2], sred[3]));
#pragma unroll
  for (int q = 0; q < 8; q++) {
    int i = t + 256 * q;
    if (i < 2000) rl[i] = expf(av[q] - amax) * gp[i];
  }
  __syncthreads();
  if (t < 100) {
    float ssum = 0.f;
#pragma unroll
    for (int s = 0; s < 20; s++) ssum += rl[s * 100 + t];
    rsinv[t] = 1.f / ssum;
  }
  __syncthreads();
#pragma unroll
  for (int q = 0; q < 8; q++) {
    int i = t + 256 * q;
    if (i < 2000) wgt[n * 2000 + i] = rl[i] * rsinv[i % 100];
  }
}

// ---------------- K4c: klein aggregation + final GEMM W2 ----------------
__global__ __launch_bounds__(256) void k4c(const float* __restrict__ f, const float* __restrict__ wgt,
                                           const float* __restrict__ W2, const float* __restrict__ b2,
                                           float* __restrict__ out) {
  __shared__ float cw[100];
  __shared__ float ol[200];
  __shared__ float sred[4];
  int bx = blockIdx.x; int n = bx / 20, s = bx % 20;
  int t = threadIdx.x; int w = t >> 6; int lane = t & 63;
  const float* fb = f + ((size_t)n * 20 + s) * 100 * 200;
  for (int bi = w * 25; bi < w * 25 + 25; bi++) {
    const float* fr = fb + bi * 200;
    float v0 = fr[lane], v1 = fr[lane + 64], v2 = fr[lane + 128];
    float v3 = (lane < 8) ? fr[lane + 192] : 0.f;
    float s2 = wred(v0 * v0 + v1 * v1 + v2 * v2 + v3 * v3);
    if (lane == 0) cw[bi] = wgt[n * 2000 + s * 100 + bi] * 2.f / (1.f + s2);
  }
  __syncthreads();
  float o = 0.f;
  if (t < 200) {
    for (int bi = 0; bi < 100; bi++) o += cw[bi] * fb[bi * 200 + t];
  }
  float ps = (t < 200) ? o * o : 0.f;
  ps = wred(ps);
  if (lane == 0) sred[w] = ps;
  __syncthreads();
  float no2 = sred[0] + sred[1] + sred[2] + sred[3];
  float denom = 1.f + sqrtf(1.f + no2);
  if (t < 200) ol[t] = o / denom;
  __syncthreads();
  const float4* ol4 = (const float4*)ol;
#pragma unroll
  for (int jj = 0; jj < 3; jj++) {
    int j = t + 256 * jj;
    const float4* wrow = (const float4*)(W2 + (size_t)j * 200);
    float a0 = 0, a1 = 0, a2 = 0, a3 = 0;
    for (int k4 = 0; k4 < 50; k4++) {
      float4 wv = wrow[k4]; float4 ov = ol4[k4];
      a0 += wv.x * ov.x; a1 += wv.y * ov.y; a2 += wv.z * ov.z; a3 += wv.w * ov.w;
    }
    out[((size_t)n * 20 + s) * 768 + j] = a0 + a1 + a2 + a3 + b2[j];
  }
}

extern "C" void kernel_launch(void* const* d_in, const int* in_sizes, int n_in,
                              void* d_out, int out_size, void* d_ws, size_t ws_size,
                              hipStream_t stream) {
  const float* x_     = (const float*)d_in[0];
  const float* W1     = (const float*)d_in[1];
  const float* b1     = (const float*)d_in[2];
  const float* W2     = (const float*)d_in[3];
  const float* b2     = (const float*)d_in[4];
  const float* Wih_f  = (const float*)d_in[5];
  const float* Whh_f  = (const float*)d_in[6];
  const float* bias_f = (const float*)d_in[7];
  const float* Wih_b  = (const float*)d_in[8];
  const float* Whh_b  = (const float*)d_in[9];
  const float* bias_b = (const float*)d_in[10];
  const float* centroid = (const float*)d_in[11];
  const float* Wp     = (const float*)d_in[12];
  const float* bp     = (const float*)d_in[13];
  const float* beta   = (const float*)d_in[14];
  float* out = (float*)d_out;
  float* ws = (float*)d_ws;
  float* p   = ws + OFF_P;
  float* ux  = ws + OFF_UX;
  float* wt4 = ws + OFF_WT4;
  float* f   = ws + OFF_F;
  float* wi4 = ws + OFF_WI4;
  float* w1p = ws + OFF_W1P;
  float* mx  = ws + OFF_MX;
  float* wp4 = ws + OFF_WP4;
  float* cl  = ws + OFF_CL;
  float* aa  = ws + OFF_A;
  float* gg  = ws + OFF_G;
  float* wg  = ws + OFF_WGT;

  (void)hipFuncSetAttribute(reinterpret_cast<const void*>(k3),
                            hipFuncAttributeMaxDynamicSharedMemorySize, K3_LDS_BYTES);
  (void)hipFuncSetAttribute(reinterpret_cast<const void*>(k2),
                            hipFuncAttributeMaxDynamicSharedMemorySize, K2_LDS_BYTES);
  (void)hipFuncSetAttribute(reinterpret_cast<const void*>(k4ag),
                            hipFuncAttributeMaxDynamicSharedMemorySize, K4G_LDS_BYTES);

  k0_pack<<<925, 256, 0, stream>>>(Whh_f, Whh_b, Wih_f, Wih_b, W1, Wp, wt4, wi4, w1p, wp4);
  k0_cl<<<1, 256, 0, stream>>>(centroid, cl);
  k1<<<500, 256, 0, stream>>>(x_, w1p, b1, p);
  k2<<<3000, 256, K2_LDS_BYTES, stream>>>(p, wi4, ux);
  k3<<<256, 1024, K3_LDS_BYTES, stream>>>(ux, wt4, bias_f, bias_b, f);
  k4ag<<<1000, 256, K4G_LDS_BYTES, stream>>>(f, wp4, mx);
  k4ae<<<500, 256, 0, stream>>>(f, mx, bp, cl, beta, aa, gg);
  k4b<<<16, 256, 0, stream>>>(aa, gg, wg);
  k4c<<<320, 256, 0, stream>>>(f, wg, W2, b2, out);
}